// Round 10
// baseline (380.883 us; speedup 1.0000x reference)
//
#include <hip/hip_runtime.h>

#define BB 64
#define TT 2048
#define DD 512
#define UU 32

// ---------------------------------------------------------------------------
// K1: logits[b,t,u] = sum_k x[b,t,k]*kernel[k,u] + bias[u]  (R7-verified)
// ---------------------------------------------------------------------------
__global__ __launch_bounds__(256, 4) void k1_logits(const float* __restrict__ x,
                                                    const float* __restrict__ w,
                                                    const float* __restrict__ bias,
                                                    float* __restrict__ out) {
  __shared__ float xs[128 * 34];
  __shared__ float wsh[32 * 36];
  const int tid = threadIdx.x;
  const long row0 = (long)blockIdx.x * 128;
  const int tr = tid >> 2;          // 0..63
  const int tc = tid & 3;
  const int ubase = tc * 8;
  const int sr = tid >> 3;          // 0..31
  const int sc = (tid & 7) * 4;

  float2 acc2[2][4];
#pragma unroll
  for (int i = 0; i < 2; ++i)
#pragma unroll
    for (int j = 0; j < 4; ++j) acc2[i][j] = make_float2(0.0f, 0.0f);

  for (int kc = 0; kc < DD; kc += 32) {
#pragma unroll
    for (int p = 0; p < 4; ++p) {
      const int r = p * 32 + sr;
      const float4 v = *(const float4*)(x + (row0 + r) * DD + kc + sc);
      *(float2*)(&xs[r * 34 + sc]) = make_float2(v.x, v.y);
      *(float2*)(&xs[r * 34 + sc + 2]) = make_float2(v.z, v.w);
    }
    {
      const int k = tid >> 3;
      const int uu4 = (tid & 7) * 4;
      const float4 v = *(const float4*)(w + (size_t)(kc + k) * UU + uu4);
      *(float4*)(&wsh[k * 36 + uu4]) = v;
    }
    __syncthreads();
#pragma unroll
    for (int kp = 0; kp < 16; ++kp) {
      const int k = kp * 2;
      const float4 wa0 = *(const float4*)(&wsh[k * 36 + ubase]);
      const float4 wa1 = *(const float4*)(&wsh[k * 36 + ubase + 4]);
      const float4 wb0 = *(const float4*)(&wsh[(k + 1) * 36 + ubase]);
      const float4 wb1 = *(const float4*)(&wsh[(k + 1) * 36 + ubase + 4]);
#pragma unroll
      for (int i = 0; i < 2; ++i) {
        const float2 xv2 = *(const float2*)(&xs[(tr + 64 * i) * 34 + k]);
        acc2[i][0].x = fmaf(xv2.x, wa0.x, acc2[i][0].x);
        acc2[i][0].y = fmaf(xv2.x, wa0.y, acc2[i][0].y);
        acc2[i][1].x = fmaf(xv2.x, wa0.z, acc2[i][1].x);
        acc2[i][1].y = fmaf(xv2.x, wa0.w, acc2[i][1].y);
        acc2[i][2].x = fmaf(xv2.x, wa1.x, acc2[i][2].x);
        acc2[i][2].y = fmaf(xv2.x, wa1.y, acc2[i][2].y);
        acc2[i][3].x = fmaf(xv2.x, wa1.z, acc2[i][3].x);
        acc2[i][3].y = fmaf(xv2.x, wa1.w, acc2[i][3].y);
        acc2[i][0].x = fmaf(xv2.y, wb0.x, acc2[i][0].x);
        acc2[i][0].y = fmaf(xv2.y, wb0.y, acc2[i][0].y);
        acc2[i][1].x = fmaf(xv2.y, wb0.z, acc2[i][1].x);
        acc2[i][1].y = fmaf(xv2.y, wb0.w, acc2[i][1].y);
        acc2[i][2].x = fmaf(xv2.y, wb1.x, acc2[i][2].x);
        acc2[i][2].y = fmaf(xv2.y, wb1.y, acc2[i][2].y);
        acc2[i][3].x = fmaf(xv2.y, wb1.z, acc2[i][3].x);
        acc2[i][3].y = fmaf(xv2.y, wb1.w, acc2[i][3].y);
      }
    }
    __syncthreads();
  }
  float bv[8];
#pragma unroll
  for (int j = 0; j < 8; ++j) bv[j] = bias[ubase + j];
#pragma unroll
  for (int i = 0; i < 2; ++i) {
    const long row = row0 + tr + 64 * i;
    float4 o0, o1;
    o0.x = acc2[i][0].x + bv[0]; o0.y = acc2[i][0].y + bv[1];
    o0.z = acc2[i][1].x + bv[2]; o0.w = acc2[i][1].y + bv[3];
    o1.x = acc2[i][2].x + bv[4]; o1.y = acc2[i][2].y + bv[5];
    o1.z = acc2[i][3].x + bv[6]; o1.w = acc2[i][3].y + bv[7];
    *(float4*)(out + row * UU + ubase) = o0;
    *(float4*)(out + row * UU + ubase + 4) = o1;
  }
}

// ---------------------------------------------------------------------------
// K2: Viterbi forward — DUAL-CHAIN wave. Chain A in lanes 0-31, chain B in
// lanes 32-63; alpha in NATURAL layout (lane holds alpha[chain][lane&31]).
// All cross-lane ops (row_ror within 16-rows, permlane16_swap l<->l^16) stay
// inside each 32-lane half, so ONE instruction stream steps BOTH chains:
// ~84 issue slots / 2 chains = 42 slots/chain-step vs 71 in the single-chain
// S/D scheme. Output is BITWISE identical (fmax over the same 32 candidate
// values is order-invariant; each add has identical operands).
// Candidates for column u = lane&31 (q=lane&15, h16=(lane>>4)&1):
//   own row:   v = h16*16 + ((q+/-s)&15)      via ror_s(P)      + tvOwn[s]
//   other row: v = (1-h16)*16 + ((q+/-s)&15)  via ror_s(swap(P)) + tvOth[s]
// Probe-gated (row_ror direction + permlane16 semantics); fallback = verified
// R2 bpermute scheme run per-chain sequentially. 32 blocks x 64 threads.
// ---------------------------------------------------------------------------
__global__ __launch_bounds__(64) void k2_forward(float* __restrict__ lb,
                                                 const float* __restrict__ trans,
                                                 const int* __restrict__ nwords) {
  const int lane = threadIdx.x;
  const int q = lane & 15;
  const int h16 = (lane >> 4) & 1;
  const int col = lane & 31;
  const int bA = blockIdx.x * 2;

  const int probe = __builtin_amdgcn_update_dpp(0, q, 0x121, 0xF, 0xF, false);
  const bool dirp = (probe == ((q + 1) & 15));

  float bufA[16], bufB[16];

#if __has_builtin(__builtin_amdgcn_permlane16_swap)
  typedef unsigned int v2u __attribute__((ext_vector_type(2)));
  v2u p16 = __builtin_amdgcn_permlane16_swap((unsigned)lane, (unsigned)lane, false, false);
  const bool c16ok = ((int)p16.x == (lane ^ 16)) || ((int)p16.y == (lane ^ 16));
  const bool m16sel = ((int)p16.x == (lane ^ 16));
  const bool okNew = (__ballot(c16ok) == ~0ull);

  if (okNew) {
    // tables
    float tvOwn[16], tvOth[16];
#pragma unroll
    for (int s = 0; s < 16; ++s) {
      const int rps = dirp ? ((q + s) & 15) : ((q - s) & 15);
      tvOwn[s] = trans[(h16 * 16 + rps) * UU + col];
      tvOth[s] = trans[((1 - h16) * 16 + rps) * UU + col];
    }
    // per-lane pointer: this lane's chain + column
    float* pl = lb + (size_t)(bA + (lane >> 5)) * TT * UU + col;
    float P = pl[0];  // alpha0 = logits row 0 (natural layout)

#define ROTP(S) \
  __int_as_float(__builtin_amdgcn_update_dpp(0, __float_as_int(P), 0x120 + (S), 0xF, 0xF, true))
#define ROTX(S) \
  __int_as_float(__builtin_amdgcn_update_dpp(0, __float_as_int(x_), 0x120 + (S), 0xF, 0xF, true))

#define K2_STEP2(tval, lg) do {                                              \
    v2u sw_ = __builtin_amdgcn_permlane16_swap(__float_as_uint(P),           \
                                               __float_as_uint(P), false, false); \
    const float x_ = m16sel ? __uint_as_float(sw_.x) : __uint_as_float(sw_.y); \
    const float a0 = P + tvOwn[0];                                           \
    const float a1 = ROTP(1) + tvOwn[1];                                     \
    const float a2 = ROTP(2) + tvOwn[2];                                     \
    const float a3 = ROTP(3) + tvOwn[3];                                     \
    const float a4 = ROTP(4) + tvOwn[4];                                     \
    const float a5 = ROTP(5) + tvOwn[5];                                     \
    const float a6 = ROTP(6) + tvOwn[6];                                     \
    const float a7 = ROTP(7) + tvOwn[7];                                     \
    const float a8 = ROTP(8) + tvOwn[8];                                     \
    const float a9 = ROTP(9) + tvOwn[9];                                     \
    const float a10 = ROTP(10) + tvOwn[10];                                  \
    const float a11 = ROTP(11) + tvOwn[11];                                  \
    const float a12 = ROTP(12) + tvOwn[12];                                  \
    const float a13 = ROTP(13) + tvOwn[13];                                  \
    const float a14 = ROTP(14) + tvOwn[14];                                  \
    const float a15 = ROTP(15) + tvOwn[15];                                  \
    const float b0 = x_ + tvOth[0];                                          \
    const float b1 = ROTX(1) + tvOth[1];                                     \
    const float b2 = ROTX(2) + tvOth[2];                                     \
    const float b3 = ROTX(3) + tvOth[3];                                     \
    const float b4 = ROTX(4) + tvOth[4];                                     \
    const float b5 = ROTX(5) + tvOth[5];                                     \
    const float b6 = ROTX(6) + tvOth[6];                                     \
    const float b7 = ROTX(7) + tvOth[7];                                     \
    const float b8 = ROTX(8) + tvOth[8];                                     \
    const float b9 = ROTX(9) + tvOth[9];                                     \
    const float b10 = ROTX(10) + tvOth[10];                                  \
    const float b11 = ROTX(11) + tvOth[11];                                  \
    const float b12 = ROTX(12) + tvOth[12];                                  \
    const float b13 = ROTX(13) + tvOth[13];                                  \
    const float b14 = ROTX(14) + tvOth[14];                                  \
    const float b15 = ROTX(15) + tvOth[15];                                  \
    const float t0 = fmaxf(fmaxf(a0, a1), a2);                               \
    const float t1 = fmaxf(fmaxf(a3, a4), a5);                               \
    const float t2 = fmaxf(fmaxf(a6, a7), a8);                               \
    const float t3 = fmaxf(fmaxf(a9, a10), a11);                             \
    const float t4 = fmaxf(fmaxf(a12, a13), a14);                            \
    const float t5 = fmaxf(fmaxf(a15, b0), b1);                              \
    const float t6 = fmaxf(fmaxf(b2, b3), b4);                               \
    const float t7 = fmaxf(fmaxf(b5, b6), b7);                               \
    const float t8 = fmaxf(fmaxf(b8, b9), b10);                              \
    const float t9 = fmaxf(fmaxf(b11, b12), b13);                            \
    const float t10 = fmaxf(b14, b15);                                       \
    const float u0 = fmaxf(fmaxf(t0, t1), t2);                               \
    const float u1 = fmaxf(fmaxf(t3, t4), t5);                               \
    const float u2 = fmaxf(fmaxf(t6, t7), t8);                               \
    const float u3 = fmaxf(t9, t10);                                         \
    const float pm = fmaxf(fmaxf(u0, u1), fmaxf(u2, u3));                    \
    P = pm + (lg);                                                           \
    pl[(size_t)(tval) * UU] = P;                                             \
  } while (0)

#pragma unroll
    for (int i = 0; i < 16; ++i) bufA[i] = pl[(size_t)(1 + i) * UU];
#pragma unroll 1
    for (int tc = 1; tc <= 1985; tc += 32) {
#pragma unroll
      for (int i = 0; i < 16; ++i) bufB[i] = pl[(size_t)(tc + 16 + i) * UU];
#pragma unroll
      for (int i = 0; i < 16; ++i) K2_STEP2(tc + i, bufA[i]);
#pragma unroll
      for (int i = 0; i < 16; ++i) bufA[i] = pl[(size_t)(tc + 32 + i) * UU];
#pragma unroll
      for (int i = 0; i < 16; ++i) K2_STEP2(tc + 16 + i, bufB[i]);
    }
    // peeled tail: tc = 2017; bufA holds rows 2017..2032
#pragma unroll
    for (int i = 0; i < 16; ++i) {
      int r = 2033 + i; if (r > TT - 1) r = TT - 1;
      bufB[i] = pl[(size_t)r * UU];
    }
#pragma unroll
    for (int i = 0; i < 16; ++i) K2_STEP2(2017 + i, bufA[i]);
#pragma unroll
    for (int i = 0; i < 15; ++i) K2_STEP2(2033 + i, bufB[i]);
    return;
  }
#endif

  // ---------------- fallback: R2 bpermute alternating S/D scheme, one chain
  // at a time with the full 64-lane wave (verified; dead code when probes pass)
  {
    const int bit4 = (lane >> 4) & 1;
    const int bit5v = (lane >> 5) & 1;
    const int hiS = bit4 ^ bit5v;
    const int tgtS = bit4 * 16 + q;
    const int cstoS = hiS * 16 + q;
    const int idx32 = (lane ^ 32) << 2;
    const int idx48 = (lane ^ 48) << 2;

    float tvS[16], tvD[16];
#pragma unroll
    for (int s = 0; s < 16; ++s) {
      const int rp = dirp ? ((q + s) & 15) : ((q - s) & 15);
      tvS[s] = trans[(hiS * 16 + rp) * UU + tgtS];
      tvD[s] = trans[(bit4 * 16 + rp) * UU + cstoS];
    }

#define ROTF(S) \
  __int_as_float(__builtin_amdgcn_update_dpp(0, __float_as_int(P), 0x120 + (S), 0xF, 0xF, true))

#define K2_BSTEP(tval, lg, TVHI, XIDX, SCOL) do {                            \
    const float g0 = P + (TVHI)[0];                                          \
    const float g1 = ROTF(1) + (TVHI)[1];                                    \
    const float g2 = ROTF(2) + (TVHI)[2];                                    \
    const float g3 = ROTF(3) + (TVHI)[3];                                    \
    const float g4 = ROTF(4) + (TVHI)[4];                                    \
    const float g5 = ROTF(5) + (TVHI)[5];                                    \
    const float g6 = ROTF(6) + (TVHI)[6];                                    \
    const float g7 = ROTF(7) + (TVHI)[7];                                    \
    const float g8 = ROTF(8) + (TVHI)[8];                                    \
    const float g9 = ROTF(9) + (TVHI)[9];                                    \
    const float g10 = ROTF(10) + (TVHI)[10];                                 \
    const float g11 = ROTF(11) + (TVHI)[11];                                 \
    const float g12 = ROTF(12) + (TVHI)[12];                                 \
    const float g13 = ROTF(13) + (TVHI)[13];                                 \
    const float g14 = ROTF(14) + (TVHI)[14];                                 \
    const float g15 = ROTF(15) + (TVHI)[15];                                 \
    const float h0 = fmaxf(fmaxf(g0, g1), g2);                               \
    const float h1 = fmaxf(fmaxf(g3, g4), g5);                               \
    const float h2 = fmaxf(fmaxf(g6, g7), g8);                               \
    const float h3 = fmaxf(fmaxf(g9, g10), g11);                             \
    const float h4 = fmaxf(fmaxf(g12, g13), g14);                            \
    const float k0 = fmaxf(fmaxf(h0, h1), h2);                               \
    const float k1 = fmaxf(fmaxf(h3, h4), g15);                              \
    const float pm2 = fmaxf(k0, k1);                                         \
    const int po = __builtin_amdgcn_ds_bpermute((XIDX), __float_as_int(pm2));\
    P = fmaxf(pm2, __int_as_float(po)) + (lg);                               \
    base[(size_t)(tval) * UU + (SCOL)] = P;                                  \
  } while (0)

    for (int cb = 0; cb < 2; ++cb) {
      float* base = lb + (size_t)(bA + cb) * TT * UU;
      float P = base[cstoS];
#pragma unroll
      for (int i = 0; i < 16; ++i)
        bufA[i] = base[(size_t)(1 + i) * UU + ((i & 1) ? cstoS : tgtS)];
#pragma unroll 1
      for (int tc = 1; tc <= 1985; tc += 32) {
#pragma unroll
        for (int i = 0; i < 16; ++i)
          bufB[i] = base[(size_t)(tc + 16 + i) * UU + ((i & 1) ? cstoS : tgtS)];
#pragma unroll
        for (int i = 0; i < 16; ++i) {
          if ((i & 1) == 0) K2_BSTEP(tc + i, bufA[i], tvS, idx32, tgtS);
          else              K2_BSTEP(tc + i, bufA[i], tvD, idx48, cstoS);
        }
#pragma unroll
        for (int i = 0; i < 16; ++i)
          bufA[i] = base[(size_t)(tc + 32 + i) * UU + ((i & 1) ? cstoS : tgtS)];
#pragma unroll
        for (int i = 0; i < 16; ++i) {
          if ((i & 1) == 0) K2_BSTEP(tc + 16 + i, bufB[i], tvS, idx32, tgtS);
          else              K2_BSTEP(tc + 16 + i, bufB[i], tvD, idx48, cstoS);
        }
      }
#pragma unroll
      for (int i = 0; i < 16; ++i) {
        int r = 2033 + i; if (r > TT - 1) r = TT - 1;
        bufB[i] = base[(size_t)r * UU + ((i & 1) ? cstoS : tgtS)];
      }
#pragma unroll
      for (int i = 0; i < 16; ++i) {
        if ((i & 1) == 0) K2_BSTEP(2017 + i, bufA[i], tvS, idx32, tgtS);
        else              K2_BSTEP(2017 + i, bufA[i], tvD, idx48, cstoS);
      }
#pragma unroll
      for (int i = 0; i < 15; ++i) {
        if ((i & 1) == 0) K2_BSTEP(2033 + i, bufB[i], tvS, idx32, tgtS);
        else              K2_BSTEP(2033 + i, bufB[i], tvD, idx48, cstoS);
      }
    }
  }
}

// ---------------------------------------------------------------------------
// K3: backpointers, fully parallel from stored alpha rows.  (unchanged)
// ---------------------------------------------------------------------------
__global__ __launch_bounds__(256) void k3_bp(const float* __restrict__ lb,
                                             const float* __restrict__ trans,
                                             const int* __restrict__ nwords,
                                             unsigned char* __restrict__ bp) {
  __shared__ float as[129 * 32];
  __shared__ float ts[32 * 32];
  const int b = blockIdx.x >> 4;
  const int c = blockIdx.x & 15;
  const int t0 = 128 * c;
  const int tid = threadIdx.x;
  const float* base = lb + (size_t)b * TT * UU;
  const int nw = nwords[b];

  for (int idx = tid; idx < 129 * 32; idx += 256) {
    const int gidx = (t0 - 1) * 32 + idx;
    as[idx] = (gidx >= 0 && gidx < TT * UU) ? base[gidx] : 0.0f;
  }
  for (int idx = tid; idx < 1024; idx += 256) ts[idx] = trans[idx];
  __syncthreads();

  const int u = tid & 31;
  const int tg = tid >> 5;
  unsigned char* bpu = bp + ((size_t)b * 32 + u) * TT;

#pragma unroll 1
  for (int qq = 0; qq < 4; ++qq) {
    const int tl0 = tg * 16 + qq * 4;
    unsigned int pack = 0;
#pragma unroll
    for (int e = 0; e < 4; ++e) {
      const int tl = tl0 + e;
      const int t = t0 + tl;
      int idx;
      if (t >= 1 && t < nw) {
        float m = as[tl * 32 + 0] + ts[0 * 32 + u];
        idx = 0;
#pragma unroll
        for (int v = 1; v < 32; ++v) {
          const float cv = as[tl * 32 + v] + ts[v * 32 + u];
          if (cv > m) { m = cv; idx = v; }
        }
      } else {
        idx = u;
      }
      pack |= ((unsigned int)idx) << (8 * e);
    }
    *(unsigned int*)(bpu + t0 + tl0) = pack;
  }
}

// ---------------------------------------------------------------------------
// K4: backtrace + best_score. One wave per chain.  (R7 guard-split version)
// ---------------------------------------------------------------------------
__global__ __launch_bounds__(64) void k4_backtrace(const float* __restrict__ lb,
                                                   const unsigned char* __restrict__ bp,
                                                   const int* __restrict__ nwords,
                                                   int* __restrict__ pred,
                                                   float* __restrict__ score) {
  const int b = blockIdx.x;
  const int lane = threadIdx.x;
  const int u = lane & 31;
  const int h = lane >> 5;
  const int nw = nwords[b];

  const float a = lb[((size_t)b * TT + (nw - 1)) * UU + u];
  float m = a;
#pragma unroll
  for (int s = 32; s; s >>= 1) m = fmaxf(m, __shfl_xor(m, s));
  if (lane == 0) score[b] = m;
  const unsigned long long mask = __ballot(lane < 32 && a == m);
  int tag = __ffsll((unsigned long long)mask) - 1;
  tag = __builtin_amdgcn_readfirstlane(tag);

  int* predb = pred + b * TT;
  for (int p = nw - 1 + lane; p < TT; p += 64) predb[p] = tag;
  if (nw < 2) return;

  const unsigned char* bpb = bp + (size_t)b * 32 * TT;
  const int pcmax = (nw - 2) >> 6;
  const int thi_top = nw - 1;

  int wprev0 = 0;
  {
    const int toff = (pcmax + 1) * 64;
    if (toff < TT) wprev0 = *(const int*)(bpb + (size_t)u * TT + toff);
  }

  for (int pc = pcmax; pc >= 0; --pc) {
    int wreg[8];
#pragma unroll
    for (int j = 0; j < 8; ++j)
      wreg[j] = *(const int*)(bpb + (size_t)u * TT + pc * 64 + 4 * (h * 8 + j));
    int predv = 0;

    if (pc == pcmax) {
      const int thi = thi_top;
      if (pc * 64 + 64 <= thi) {
        const int val = __builtin_amdgcn_readlane(wprev0, tag);
        tag = __builtin_amdgcn_readfirstlane(val & 0xFF);
        if (lane == 63) predv = tag;
      }
#pragma unroll
      for (int lt = 63; lt >= 1; --lt) {
        if (pc * 64 + lt <= thi) {
          const int d = lt >> 2, byte = lt & 3;
          const int hs = d >> 3, j = d & 7;
          const int val = __builtin_amdgcn_readlane(wreg[j], hs * 32 + tag);
          tag = __builtin_amdgcn_readfirstlane((val >> (8 * byte)) & 0xFF);
          if (lane == lt - 1) predv = tag;
        }
      }
      const int lim = thi - pc * 64;
      if (lane < lim) predb[pc * 64 + lane] = predv;
    } else {
      {
        const int val = __builtin_amdgcn_readlane(wprev0, tag);
        tag = __builtin_amdgcn_readfirstlane(val & 0xFF);
        if (lane == 63) predv = tag;
      }
#pragma unroll
      for (int lt = 63; lt >= 1; --lt) {
        const int d = lt >> 2, byte = lt & 3;
        const int hs = d >> 3, j = d & 7;
        const int val = __builtin_amdgcn_readlane(wreg[j], hs * 32 + tag);
        tag = __builtin_amdgcn_readfirstlane((val >> (8 * byte)) & 0xFF);
        if (lane == lt - 1) predv = tag;
      }
      predb[pc * 64 + lane] = predv;
    }
    wprev0 = wreg[0];
  }
}

// ---------------------------------------------------------------------------
extern "C" void kernel_launch(void* const* d_in, const int* in_sizes, int n_in,
                              void* d_out, int out_size, void* d_ws, size_t ws_size,
                              hipStream_t stream) {
  const float* x = (const float*)d_in[0];
  const int* nwords = (const int*)d_in[1];
  const float* kern = (const float*)d_in[2];
  const float* chain = (const float*)d_in[3];
  const float* bias = (const float*)d_in[4];

  float* logits = (float*)d_ws;                                        // 16 MB
  unsigned char* bp = (unsigned char*)d_ws + (size_t)BB * TT * UU * 4; // +4 MB

  int* pred = (int*)d_out;
  float* score = (float*)d_out + (size_t)BB * TT;

  k1_logits<<<dim3(1024), dim3(256), 0, stream>>>(x, kern, bias, logits);
  k2_forward<<<dim3(BB / 2), dim3(64), 0, stream>>>(logits, chain, nwords);
  k3_bp<<<dim3(BB * 16), dim3(256), 0, stream>>>(logits, chain, nwords, bp);
  k4_backtrace<<<dim3(BB), dim3(64), 0, stream>>>(logits, bp, nwords, pred, score);
}

// Round 11
// 247.653 us; speedup vs baseline: 1.5380x; 1.5380x over previous
//
#include <hip/hip_runtime.h>

#define BB 64
#define TT 2048
#define DD 512
#define UU 32

// per-chain fixup results: rows > g_ts[b] need +g_c[b]. Written by k2b every
// launch (defaults at entry), read by k2c. Kernel-boundary ordering on the
// stream makes this safe under graph replay.
__device__ int g_ts[BB];
__device__ float g_c[BB];

// ---------------------------------------------------------------------------
// K1: logits[b,t,u] = sum_k x[b,t,k]*kernel[k,u] + bias[u]  (R7-verified)
// ---------------------------------------------------------------------------
__global__ __launch_bounds__(256, 4) void k1_logits(const float* __restrict__ x,
                                                    const float* __restrict__ w,
                                                    const float* __restrict__ bias,
                                                    float* __restrict__ out) {
  __shared__ float xs[128 * 34];
  __shared__ float wsh[32 * 36];
  const int tid = threadIdx.x;
  const long row0 = (long)blockIdx.x * 128;
  const int tr = tid >> 2;          // 0..63
  const int tc = tid & 3;
  const int ubase = tc * 8;
  const int sr = tid >> 3;          // 0..31
  const int sc = (tid & 7) * 4;

  float2 acc2[2][4];
#pragma unroll
  for (int i = 0; i < 2; ++i)
#pragma unroll
    for (int j = 0; j < 4; ++j) acc2[i][j] = make_float2(0.0f, 0.0f);

  for (int kc = 0; kc < DD; kc += 32) {
#pragma unroll
    for (int p = 0; p < 4; ++p) {
      const int r = p * 32 + sr;
      const float4 v = *(const float4*)(x + (row0 + r) * DD + kc + sc);
      *(float2*)(&xs[r * 34 + sc]) = make_float2(v.x, v.y);
      *(float2*)(&xs[r * 34 + sc + 2]) = make_float2(v.z, v.w);
    }
    {
      const int k = tid >> 3;
      const int uu4 = (tid & 7) * 4;
      const float4 v = *(const float4*)(w + (size_t)(kc + k) * UU + uu4);
      *(float4*)(&wsh[k * 36 + uu4]) = v;
    }
    __syncthreads();
#pragma unroll
    for (int kp = 0; kp < 16; ++kp) {
      const int k = kp * 2;
      const float4 wa0 = *(const float4*)(&wsh[k * 36 + ubase]);
      const float4 wa1 = *(const float4*)(&wsh[k * 36 + ubase + 4]);
      const float4 wb0 = *(const float4*)(&wsh[(k + 1) * 36 + ubase]);
      const float4 wb1 = *(const float4*)(&wsh[(k + 1) * 36 + ubase + 4]);
#pragma unroll
      for (int i = 0; i < 2; ++i) {
        const float2 xv2 = *(const float2*)(&xs[(tr + 64 * i) * 34 + k]);
        acc2[i][0].x = fmaf(xv2.x, wa0.x, acc2[i][0].x);
        acc2[i][0].y = fmaf(xv2.x, wa0.y, acc2[i][0].y);
        acc2[i][1].x = fmaf(xv2.x, wa0.z, acc2[i][1].x);
        acc2[i][1].y = fmaf(xv2.x, wa0.w, acc2[i][1].y);
        acc2[i][2].x = fmaf(xv2.x, wa1.x, acc2[i][2].x);
        acc2[i][2].y = fmaf(xv2.x, wa1.y, acc2[i][2].y);
        acc2[i][3].x = fmaf(xv2.x, wa1.z, acc2[i][3].x);
        acc2[i][3].y = fmaf(xv2.x, wa1.w, acc2[i][3].y);
        acc2[i][0].x = fmaf(xv2.y, wb0.x, acc2[i][0].x);
        acc2[i][0].y = fmaf(xv2.y, wb0.y, acc2[i][0].y);
        acc2[i][1].x = fmaf(xv2.y, wb0.z, acc2[i][1].x);
        acc2[i][1].y = fmaf(xv2.y, wb0.w, acc2[i][1].y);
        acc2[i][2].x = fmaf(xv2.y, wb1.x, acc2[i][2].x);
        acc2[i][2].y = fmaf(xv2.y, wb1.y, acc2[i][2].y);
        acc2[i][3].x = fmaf(xv2.y, wb1.z, acc2[i][3].x);
        acc2[i][3].y = fmaf(xv2.y, wb1.w, acc2[i][3].y);
      }
    }
    __syncthreads();
  }
  float bv[8];
#pragma unroll
  for (int j = 0; j < 8; ++j) bv[j] = bias[ubase + j];
#pragma unroll
  for (int i = 0; i < 2; ++i) {
    const long row = row0 + tr + 64 * i;
    float4 o0, o1;
    o0.x = acc2[i][0].x + bv[0]; o0.y = acc2[i][0].y + bv[1];
    o0.z = acc2[i][1].x + bv[2]; o0.w = acc2[i][1].y + bv[3];
    o1.x = acc2[i][2].x + bv[4]; o1.y = acc2[i][2].y + bv[5];
    o1.z = acc2[i][3].x + bv[6]; o1.w = acc2[i][3].y + bv[7];
    *(float4*)(out + row * UU + ubase) = o0;
    *(float4*)(out + row * UU + ubase + 4) = o1;
  }
}

// ======================= K2 common machinery (R7-verified) ==================

#define ROTF(S) \
  __int_as_float(__builtin_amdgcn_update_dpp(0, __float_as_int(P), 0x120 + (S), 0xF, 0xF, true))

#define K2_TREE                                                              \
    const float c0 = P + tvS[0];                                             \
    const float c1 = ROTF(1) + tvS[1];                                       \
    const float c2 = ROTF(2) + tvS[2];                                       \
    const float c3 = ROTF(3) + tvS[3];                                       \
    const float c4 = ROTF(4) + tvS[4];                                       \
    const float c5 = ROTF(5) + tvS[5];                                       \
    const float c6 = ROTF(6) + tvS[6];                                       \
    const float c7 = ROTF(7) + tvS[7];                                       \
    const float c8 = ROTF(8) + tvS[8];                                       \
    const float c9 = ROTF(9) + tvS[9];                                       \
    const float c10 = ROTF(10) + tvS[10];                                    \
    const float c11 = ROTF(11) + tvS[11];                                    \
    const float c12 = ROTF(12) + tvS[12];                                    \
    const float c13 = ROTF(13) + tvS[13];                                    \
    const float c14 = ROTF(14) + tvS[14];                                    \
    const float c15 = ROTF(15) + tvS[15];                                    \
    const float d0 = fmaxf(fmaxf(c0, c1), c2);                               \
    const float d1 = fmaxf(fmaxf(c3, c4), c5);                               \
    const float d2 = fmaxf(fmaxf(c6, c7), c8);                               \
    const float d3 = fmaxf(fmaxf(c9, c10), c11);                             \
    const float d4 = fmaxf(fmaxf(c12, c13), c14);                            \
    const float e0 = fmaxf(fmaxf(d0, d1), d2);                               \
    const float e1 = fmaxf(fmaxf(d3, d4), c15);                              \
    const float pm = fmaxf(e0, e1);

#if __has_builtin(__builtin_amdgcn_permlane32_swap) && __has_builtin(__builtin_amdgcn_permlane16_swap)
#define K2_HAVE_PERMLANE 1
typedef unsigned int v2u __attribute__((ext_vector_type(2)));

#define K2_FSTEP(tval, lg) do {                                              \
    K2_TREE                                                                  \
    v2u s32 = __builtin_amdgcn_permlane32_swap(__float_as_uint(pm),          \
                                               __float_as_uint(pm), false, false); \
    const float pd = fmaxf(__uint_as_float(s32.x), __uint_as_float(s32.y)) + (lg); \
    v2u s16 = __builtin_amdgcn_permlane16_swap(__float_as_uint(pd),          \
                                               __float_as_uint(pd), false, false); \
    const float cx = m16sel ? __uint_as_float(s16.x) : __uint_as_float(s16.y); \
    P = bit5v ? cx : pd;                                                     \
    base[(size_t)(tval) * UU + cstoS] = P;                                   \
  } while (0)

// combined pre-logit max (bitwise-identical tree + swap32 fold of K2_FSTEP)
__device__ __forceinline__ float k2_mcomb(float P, const float* tvS) {
  K2_TREE
  v2u s32 = __builtin_amdgcn_permlane32_swap(__float_as_uint(pm),
                                             __float_as_uint(pm), false, false);
  return fmaxf(__uint_as_float(s32.x), __uint_as_float(s32.y));
}
#endif

// ---------------------------------------------------------------------------
// K2a: phase A. 128 blocks: role 0 (blocks 0-63) = TRUE rows 1..1024 (verified
// step code, bounds-trimmed). role 1 (blocks 64-127) = SPECULATIVE rows
// 1026..2047 from a fresh start at logits[1025] (row 1025 untouched by both
// roles => no cross-block row conflicts). Max-plus shift-invariance: spec
// differs from true by a per-row offset that becomes UNIFORM after coupling;
// k2b finds it, k2c applies it.
// ---------------------------------------------------------------------------
__global__ __launch_bounds__(64) void k2a_forward(float* __restrict__ lb,
                                                  const float* __restrict__ trans) {
  const int lane = threadIdx.x;
  const int q = lane & 15;
  const int bit4 = (lane >> 4) & 1;
  const int bit5v = (lane >> 5) & 1;
  const int hiS = bit4 ^ bit5v;
  const int tgtS = bit4 * 16 + q;
  const int cstoS = hiS * 16 + q;
  const int role = blockIdx.x >> 6;
  const int b = blockIdx.x & 63;

  const int probe = __builtin_amdgcn_update_dpp(0, q, 0x121, 0xF, 0xF, false);
  const bool dirp = (probe == ((q + 1) & 15));

  float tvS[16];
#pragma unroll
  for (int s = 0; s < 16; ++s) {
    const int rp = dirp ? ((q + s) & 15) : ((q - s) & 15);
    tvS[s] = trans[(hiS * 16 + rp) * UU + tgtS];
  }

  float* base = lb + (size_t)b * TT * UU;
  float bufA[16], bufB[16];

#ifdef K2_HAVE_PERMLANE
  v2u p32 = __builtin_amdgcn_permlane32_swap((unsigned)lane, (unsigned)lane, false, false);
  v2u p16 = __builtin_amdgcn_permlane16_swap((unsigned)lane, (unsigned)lane, false, false);
  const bool c32ok = ((int)p32.x == (lane ^ 32)) || ((int)p32.y == (lane ^ 32));
  const bool c16ok = ((int)p16.x == (lane ^ 16)) || ((int)p16.y == (lane ^ 16));
  const bool m16sel = ((int)p16.x == (lane ^ 16));
  const bool okSwap = (__ballot(c32ok) == ~0ull) && (__ballot(c16ok) == ~0ull);

  if (okSwap) {
    if (role == 0) {
      // ---- true prefix: rows 1..1024 (32 chunks of 32 steps) ----
      float P = base[cstoS];
#pragma unroll
      for (int i = 0; i < 16; ++i) bufA[i] = base[(size_t)(1 + i) * UU + tgtS];
#pragma unroll 1
      for (int tc = 1; tc <= 993; tc += 32) {
#pragma unroll
        for (int i = 0; i < 16; ++i) bufB[i] = base[(size_t)(tc + 16 + i) * UU + tgtS];
#pragma unroll
        for (int i = 0; i < 16; ++i) K2_FSTEP(tc + i, bufA[i]);
#pragma unroll
        for (int i = 0; i < 16; ++i) bufA[i] = base[(size_t)(tc + 32 + i) * UU + tgtS];
#pragma unroll
        for (int i = 0; i < 16; ++i) K2_FSTEP(tc + 16 + i, bufB[i]);
      }
    } else {
      // ---- speculative suffix: fresh start at logits[1025]; rows 1026..2047
      float P = base[(size_t)1025 * UU + cstoS];
#pragma unroll
      for (int i = 0; i < 16; ++i) bufA[i] = base[(size_t)(1026 + i) * UU + tgtS];
#pragma unroll 1
      for (int tc = 1026; tc <= 1986; tc += 32) {
#pragma unroll
        for (int i = 0; i < 16; ++i) bufB[i] = base[(size_t)(tc + 16 + i) * UU + tgtS];
#pragma unroll
        for (int i = 0; i < 16; ++i) K2_FSTEP(tc + i, bufA[i]);
#pragma unroll
        for (int i = 0; i < 16; ++i) bufA[i] = base[(size_t)(tc + 32 + i) * UU + tgtS];
#pragma unroll
        for (int i = 0; i < 16; ++i) K2_FSTEP(tc + 16 + i, bufB[i]);
      }
      // tail: bufA holds rows 2018..2033; 30 remaining steps
#pragma unroll
      for (int i = 0; i < 16; ++i) {
        int r = 2034 + i; if (r > TT - 1) r = TT - 1;
        bufB[i] = base[(size_t)r * UU + tgtS];
      }
#pragma unroll
      for (int i = 0; i < 16; ++i) K2_FSTEP(2018 + i, bufA[i]);
#pragma unroll
      for (int i = 0; i < 14; ++i) K2_FSTEP(2034 + i, bufB[i]);
    }
    return;
  }
#endif

  // ---------------- fallback: R2 bpermute alternating S/D scheme, FULL chain
  // (role 1 idles; k2b leaves defaults so k2c is a no-op) -------------------
  if (role == 1) return;
  {
    float tvD[16];
#pragma unroll
    for (int s = 0; s < 16; ++s) {
      const int rp = dirp ? ((q + s) & 15) : ((q - s) & 15);
      tvD[s] = trans[(bit4 * 16 + rp) * UU + cstoS];
    }
    const int idx32 = (lane ^ 32) << 2;
    const int idx48 = (lane ^ 48) << 2;
    float P = base[cstoS];

#define K2_BSTEP(tval, lg, TVHI, XIDX, SCOL) do {                            \
    const float g0 = P + (TVHI)[0];                                          \
    const float g1 = ROTF(1) + (TVHI)[1];                                    \
    const float g2 = ROTF(2) + (TVHI)[2];                                    \
    const float g3 = ROTF(3) + (TVHI)[3];                                    \
    const float g4 = ROTF(4) + (TVHI)[4];                                    \
    const float g5 = ROTF(5) + (TVHI)[5];                                    \
    const float g6 = ROTF(6) + (TVHI)[6];                                    \
    const float g7 = ROTF(7) + (TVHI)[7];                                    \
    const float g8 = ROTF(8) + (TVHI)[8];                                    \
    const float g9 = ROTF(9) + (TVHI)[9];                                    \
    const float g10 = ROTF(10) + (TVHI)[10];                                 \
    const float g11 = ROTF(11) + (TVHI)[11];                                 \
    const float g12 = ROTF(12) + (TVHI)[12];                                 \
    const float g13 = ROTF(13) + (TVHI)[13];                                 \
    const float g14 = ROTF(14) + (TVHI)[14];                                 \
    const float g15 = ROTF(15) + (TVHI)[15];                                 \
    const float h0 = fmaxf(fmaxf(g0, g1), g2);                               \
    const float h1 = fmaxf(fmaxf(g3, g4), g5);                               \
    const float h2 = fmaxf(fmaxf(g6, g7), g8);                               \
    const float h3 = fmaxf(fmaxf(g9, g10), g11);                             \
    const float h4 = fmaxf(fmaxf(g12, g13), g14);                            \
    const float k0 = fmaxf(fmaxf(h0, h1), h2);                               \
    const float k1 = fmaxf(fmaxf(h3, h4), g15);                              \
    const float pm2 = fmaxf(k0, k1);                                         \
    const int po = __builtin_amdgcn_ds_bpermute((XIDX), __float_as_int(pm2));\
    P = fmaxf(pm2, __int_as_float(po)) + (lg);                               \
    base[(size_t)(tval) * UU + (SCOL)] = P;                                  \
  } while (0)

#pragma unroll
    for (int i = 0; i < 16; ++i)
      bufA[i] = base[(size_t)(1 + i) * UU + ((i & 1) ? cstoS : tgtS)];
#pragma unroll 1
    for (int tc = 1; tc <= 1985; tc += 32) {
#pragma unroll
      for (int i = 0; i < 16; ++i)
        bufB[i] = base[(size_t)(tc + 16 + i) * UU + ((i & 1) ? cstoS : tgtS)];
#pragma unroll
      for (int i = 0; i < 16; ++i) {
        if ((i & 1) == 0) K2_BSTEP(tc + i, bufA[i], tvS, idx32, tgtS);
        else              K2_BSTEP(tc + i, bufA[i], tvD, idx48, cstoS);
      }
#pragma unroll
      for (int i = 0; i < 16; ++i)
        bufA[i] = base[(size_t)(tc + 32 + i) * UU + ((i & 1) ? cstoS : tgtS)];
#pragma unroll
      for (int i = 0; i < 16; ++i) {
        if ((i & 1) == 0) K2_BSTEP(tc + 16 + i, bufB[i], tvS, idx32, tgtS);
        else              K2_BSTEP(tc + 16 + i, bufB[i], tvD, idx48, cstoS);
      }
    }
#pragma unroll
    for (int i = 0; i < 16; ++i) {
      int r = 2033 + i; if (r > TT - 1) r = TT - 1;
      bufB[i] = base[(size_t)r * UU + ((i & 1) ? cstoS : tgtS)];
    }
#pragma unroll
    for (int i = 0; i < 16; ++i) {
      if ((i & 1) == 0) K2_BSTEP(2017 + i, bufA[i], tvS, idx32, tgtS);
      else              K2_BSTEP(2017 + i, bufA[i], tvD, idx48, cstoS);
    }
#pragma unroll
    for (int i = 0; i < 15; ++i) {
      if ((i & 1) == 0) K2_BSTEP(2033 + i, bufB[i], tvS, idx32, tgtS);
      else              K2_BSTEP(2033 + i, bufB[i], tvD, idx48, cstoS);
    }
  }
}

// ---------------------------------------------------------------------------
// K2b: fixup. 64 waves. Step row 1025 normally (logit row untouched), then
// per step t>=1026: d = M(trueP) - M(specP) (logit cancels), rewrite row t as
// spec + d (== true), stop when d is lane-uniform (tau) -> record (t*, c).
// Never couples -> runs to the end storing true values (built-in fallback).
// ---------------------------------------------------------------------------
__global__ __launch_bounds__(64) void k2b_fixup(float* __restrict__ lb,
                                                const float* __restrict__ trans) {
  const int lane = threadIdx.x;
  const int b = blockIdx.x;
  if (lane == 0) { g_ts[b] = TT - 1; g_c[b] = 0.0f; }  // defaults: k2c no-op
  const int q = lane & 15;
  const int bit4 = (lane >> 4) & 1;
  const int bit5v = (lane >> 5) & 1;
  const int hiS = bit4 ^ bit5v;
  const int tgtS = bit4 * 16 + q;
  const int cstoS = hiS * 16 + q;

  const int probe = __builtin_amdgcn_update_dpp(0, q, 0x121, 0xF, 0xF, false);
  const bool dirp = (probe == ((q + 1) & 15));

  float tvS[16];
#pragma unroll
  for (int s = 0; s < 16; ++s) {
    const int rp = dirp ? ((q + s) & 15) : ((q - s) & 15);
    tvS[s] = trans[(hiS * 16 + rp) * UU + tgtS];
  }

#ifdef K2_HAVE_PERMLANE
  v2u p32 = __builtin_amdgcn_permlane32_swap((unsigned)lane, (unsigned)lane, false, false);
  v2u p16 = __builtin_amdgcn_permlane16_swap((unsigned)lane, (unsigned)lane, false, false);
  const bool c32ok = ((int)p32.x == (lane ^ 32)) || ((int)p32.y == (lane ^ 32));
  const bool c16ok = ((int)p16.x == (lane ^ 16)) || ((int)p16.y == (lane ^ 16));
  const bool m16sel = ((int)p16.x == (lane ^ 16));
  const bool okSwap = (__ballot(c32ok) == ~0ull) && (__ballot(c16ok) == ~0ull);
  if (!okSwap) return;  // fallback path computed everything true already

  float* base = lb + (size_t)b * TT * UU;
  float trueP = base[(size_t)1024 * UU + cstoS];   // true (role 0 output)
  float specP = base[(size_t)1025 * UU + cstoS];   // logits row = spec init
  const float lg1025 = base[(size_t)1025 * UU + tgtS];

  {  // verified step for t=1025 (stores true row 1025)
    float P = trueP;
    K2_FSTEP(1025, lg1025);
    trueP = P;
  }

  // ring prefetch of spec rows (cstoS column)
  float ring[4];
#pragma unroll
  for (int i = 0; i < 4; ++i) ring[i] = base[(size_t)(1026 + i) * UU + cstoS];

  const float TAU = 0.05f;
#pragma unroll 1
  for (int t = 1026; t <= TT - 1; ++t) {
    const float specRow = ring[(t - 1026) & 3];
    if (t + 4 <= TT - 1) ring[(t - 1026) & 3] = base[(size_t)(t + 4) * UU + cstoS];
    const float Mt = k2_mcomb(trueP, tvS);
    const float Ms = k2_mcomb(specP, tvS);
    const float d = Mt - Ms;
    v2u s16d = __builtin_amdgcn_permlane16_swap(__float_as_uint(d),
                                                __float_as_uint(d), false, false);
    const float dx = m16sel ? __uint_as_float(s16d.x) : __uint_as_float(s16d.y);
    const float dsel = bit5v ? dx : d;
    const float nt = specRow + dsel;
    base[(size_t)t * UU + cstoS] = nt;
    const float dref = __uint_as_float(
        (unsigned)__builtin_amdgcn_readfirstlane(__float_as_int(d)));
    const bool uni = (__ballot(fabsf(d - dref) <= TAU) == ~0ull);
    trueP = nt;
    specP = specRow;
    if (uni) {
      if (lane == 0) { g_ts[b] = t; g_c[b] = dref; }
      return;
    }
  }
#endif
}

// ---------------------------------------------------------------------------
// K2c: apply per-chain offset c to rows (t*, 2047].  ~8MB worst case.
// ---------------------------------------------------------------------------
__global__ __launch_bounds__(256) void k2c_apply(float* __restrict__ lb) {
  const int b = blockIdx.x;
  const int tstar = g_ts[b];
  const float c = g_c[b];
  const int nrows = (TT - 1) - tstar;
  if (nrows <= 0 || c == 0.0f) return;
  float4* p = (float4*)(lb + ((size_t)b * TT + tstar + 1) * UU);
  const int n4 = nrows * (UU / 4);
  for (int i = threadIdx.x; i < n4; i += 256) {
    float4 v = p[i];
    v.x += c; v.y += c; v.z += c; v.w += c;
    p[i] = v;
  }
}

// ---------------------------------------------------------------------------
// K3: backpointers, fully parallel from stored alpha rows.  (unchanged)
// ---------------------------------------------------------------------------
__global__ __launch_bounds__(256) void k3_bp(const float* __restrict__ lb,
                                             const float* __restrict__ trans,
                                             const int* __restrict__ nwords,
                                             unsigned char* __restrict__ bp) {
  __shared__ float as[129 * 32];
  __shared__ float ts[32 * 32];
  const int b = blockIdx.x >> 4;
  const int c = blockIdx.x & 15;
  const int t0 = 128 * c;
  const int tid = threadIdx.x;
  const float* base = lb + (size_t)b * TT * UU;
  const int nw = nwords[b];

  for (int idx = tid; idx < 129 * 32; idx += 256) {
    const int gidx = (t0 - 1) * 32 + idx;
    as[idx] = (gidx >= 0 && gidx < TT * UU) ? base[gidx] : 0.0f;
  }
  for (int idx = tid; idx < 1024; idx += 256) ts[idx] = trans[idx];
  __syncthreads();

  const int u = tid & 31;
  const int tg = tid >> 5;
  unsigned char* bpu = bp + ((size_t)b * 32 + u) * TT;

#pragma unroll 1
  for (int qq = 0; qq < 4; ++qq) {
    const int tl0 = tg * 16 + qq * 4;
    unsigned int pack = 0;
#pragma unroll
    for (int e = 0; e < 4; ++e) {
      const int tl = tl0 + e;
      const int t = t0 + tl;
      int idx;
      if (t >= 1 && t < nw) {
        float m = as[tl * 32 + 0] + ts[0 * 32 + u];
        idx = 0;
#pragma unroll
        for (int v = 1; v < 32; ++v) {
          const float cv = as[tl * 32 + v] + ts[v * 32 + u];
          if (cv > m) { m = cv; idx = v; }
        }
      } else {
        idx = u;
      }
      pack |= ((unsigned int)idx) << (8 * e);
    }
    *(unsigned int*)(bpu + t0 + tl0) = pack;
  }
}

// ---------------------------------------------------------------------------
// K4: backtrace + best_score. One wave per chain.  (R7 guard-split version)
// ---------------------------------------------------------------------------
__global__ __launch_bounds__(64) void k4_backtrace(const float* __restrict__ lb,
                                                   const unsigned char* __restrict__ bp,
                                                   const int* __restrict__ nwords,
                                                   int* __restrict__ pred,
                                                   float* __restrict__ score) {
  const int b = blockIdx.x;
  const int lane = threadIdx.x;
  const int u = lane & 31;
  const int h = lane >> 5;
  const int nw = nwords[b];

  const float a = lb[((size_t)b * TT + (nw - 1)) * UU + u];
  float m = a;
#pragma unroll
  for (int s = 32; s; s >>= 1) m = fmaxf(m, __shfl_xor(m, s));
  if (lane == 0) score[b] = m;
  const unsigned long long mask = __ballot(lane < 32 && a == m);
  int tag = __ffsll((unsigned long long)mask) - 1;
  tag = __builtin_amdgcn_readfirstlane(tag);

  int* predb = pred + b * TT;
  for (int p = nw - 1 + lane; p < TT; p += 64) predb[p] = tag;
  if (nw < 2) return;

  const unsigned char* bpb = bp + (size_t)b * 32 * TT;
  const int pcmax = (nw - 2) >> 6;
  const int thi_top = nw - 1;

  int wprev0 = 0;
  {
    const int toff = (pcmax + 1) * 64;
    if (toff < TT) wprev0 = *(const int*)(bpb + (size_t)u * TT + toff);
  }

  for (int pc = pcmax; pc >= 0; --pc) {
    int wreg[8];
#pragma unroll
    for (int j = 0; j < 8; ++j)
      wreg[j] = *(const int*)(bpb + (size_t)u * TT + pc * 64 + 4 * (h * 8 + j));
    int predv = 0;

    if (pc == pcmax) {
      const int thi = thi_top;
      if (pc * 64 + 64 <= thi) {
        const int val = __builtin_amdgcn_readlane(wprev0, tag);
        tag = __builtin_amdgcn_readfirstlane(val & 0xFF);
        if (lane == 63) predv = tag;
      }
#pragma unroll
      for (int lt = 63; lt >= 1; --lt) {
        if (pc * 64 + lt <= thi) {
          const int d = lt >> 2, byte = lt & 3;
          const int hs = d >> 3, j = d & 7;
          const int val = __builtin_amdgcn_readlane(wreg[j], hs * 32 + tag);
          tag = __builtin_amdgcn_readfirstlane((val >> (8 * byte)) & 0xFF);
          if (lane == lt - 1) predv = tag;
        }
      }
      const int lim = thi - pc * 64;
      if (lane < lim) predb[pc * 64 + lane] = predv;
    } else {
      {
        const int val = __builtin_amdgcn_readlane(wprev0, tag);
        tag = __builtin_amdgcn_readfirstlane(val & 0xFF);
        if (lane == 63) predv = tag;
      }
#pragma unroll
      for (int lt = 63; lt >= 1; --lt) {
        const int d = lt >> 2, byte = lt & 3;
        const int hs = d >> 3, j = d & 7;
        const int val = __builtin_amdgcn_readlane(wreg[j], hs * 32 + tag);
        tag = __builtin_amdgcn_readfirstlane((val >> (8 * byte)) & 0xFF);
        if (lane == lt - 1) predv = tag;
      }
      predb[pc * 64 + lane] = predv;
    }
    wprev0 = wreg[0];
  }
}

// ---------------------------------------------------------------------------
extern "C" void kernel_launch(void* const* d_in, const int* in_sizes, int n_in,
                              void* d_out, int out_size, void* d_ws, size_t ws_size,
                              hipStream_t stream) {
  const float* x = (const float*)d_in[0];
  const int* nwords = (const int*)d_in[1];
  const float* kern = (const float*)d_in[2];
  const float* chain = (const float*)d_in[3];
  const float* bias = (const float*)d_in[4];

  float* logits = (float*)d_ws;                                        // 16 MB
  unsigned char* bp = (unsigned char*)d_ws + (size_t)BB * TT * UU * 4; // +4 MB

  int* pred = (int*)d_out;
  float* score = (float*)d_out + (size_t)BB * TT;

  k1_logits<<<dim3(1024), dim3(256), 0, stream>>>(x, kern, bias, logits);
  k2a_forward<<<dim3(128), dim3(64), 0, stream>>>(logits, chain);
  k2b_fixup<<<dim3(BB), dim3(64), 0, stream>>>(logits, chain);
  k2c_apply<<<dim3(BB), dim3(256), 0, stream>>>(logits);
  k3_bp<<<dim3(BB * 16), dim3(256), 0, stream>>>(logits, chain, nwords, bp);
  k4_backtrace<<<dim3(BB), dim3(64), 0, stream>>>(logits, bp, nwords, pred, score);
}

// Round 13
// 209.927 us; speedup vs baseline: 1.8144x; 1.1797x over previous
//
#include <hip/hip_runtime.h>

#define BB 64
#define TT 2048
#define DD 512
#define UU 32

// per-(chain, junction) fixup: rows in (g_ts[b*3+j], segEnd_j] need +g_c[b*3+j].
// PER-SEGMENT offsets (NOT cumulative): each role's spec chain starts fresh,
// so c_j is the full true-minus-spec offset for its own segment only.
// (R12 bug: cumulative application corrupted scores by ~1472.)
__device__ int g_ts[BB * 3];
__device__ float g_c[BB * 3];

// ---------------------------------------------------------------------------
// K1: logits[b,t,u] = sum_k x[b,t,k]*kernel[k,u] + bias[u]  (R7-verified)
// ---------------------------------------------------------------------------
__global__ __launch_bounds__(256, 4) void k1_logits(const float* __restrict__ x,
                                                    const float* __restrict__ w,
                                                    const float* __restrict__ bias,
                                                    float* __restrict__ out) {
  __shared__ float xs[128 * 34];
  __shared__ float wsh[32 * 36];
  const int tid = threadIdx.x;
  const long row0 = (long)blockIdx.x * 128;
  const int tr = tid >> 2;          // 0..63
  const int tc = tid & 3;
  const int ubase = tc * 8;
  const int sr = tid >> 3;          // 0..31
  const int sc = (tid & 7) * 4;

  float2 acc2[2][4];
#pragma unroll
  for (int i = 0; i < 2; ++i)
#pragma unroll
    for (int j = 0; j < 4; ++j) acc2[i][j] = make_float2(0.0f, 0.0f);

  for (int kc = 0; kc < DD; kc += 32) {
#pragma unroll
    for (int p = 0; p < 4; ++p) {
      const int r = p * 32 + sr;
      const float4 v = *(const float4*)(x + (row0 + r) * DD + kc + sc);
      *(float2*)(&xs[r * 34 + sc]) = make_float2(v.x, v.y);
      *(float2*)(&xs[r * 34 + sc + 2]) = make_float2(v.z, v.w);
    }
    {
      const int k = tid >> 3;
      const int uu4 = (tid & 7) * 4;
      const float4 v = *(const float4*)(w + (size_t)(kc + k) * UU + uu4);
      *(float4*)(&wsh[k * 36 + uu4]) = v;
    }
    __syncthreads();
#pragma unroll
    for (int kp = 0; kp < 16; ++kp) {
      const int k = kp * 2;
      const float4 wa0 = *(const float4*)(&wsh[k * 36 + ubase]);
      const float4 wa1 = *(const float4*)(&wsh[k * 36 + ubase + 4]);
      const float4 wb0 = *(const float4*)(&wsh[(k + 1) * 36 + ubase]);
      const float4 wb1 = *(const float4*)(&wsh[(k + 1) * 36 + ubase + 4]);
#pragma unroll
      for (int i = 0; i < 2; ++i) {
        const float2 xv2 = *(const float2*)(&xs[(tr + 64 * i) * 34 + k]);
        acc2[i][0].x = fmaf(xv2.x, wa0.x, acc2[i][0].x);
        acc2[i][0].y = fmaf(xv2.x, wa0.y, acc2[i][0].y);
        acc2[i][1].x = fmaf(xv2.x, wa0.z, acc2[i][1].x);
        acc2[i][1].y = fmaf(xv2.x, wa0.w, acc2[i][1].y);
        acc2[i][2].x = fmaf(xv2.x, wa1.x, acc2[i][2].x);
        acc2[i][2].y = fmaf(xv2.x, wa1.y, acc2[i][2].y);
        acc2[i][3].x = fmaf(xv2.x, wa1.z, acc2[i][3].x);
        acc2[i][3].y = fmaf(xv2.x, wa1.w, acc2[i][3].y);
        acc2[i][0].x = fmaf(xv2.y, wb0.x, acc2[i][0].x);
        acc2[i][0].y = fmaf(xv2.y, wb0.y, acc2[i][0].y);
        acc2[i][1].x = fmaf(xv2.y, wb0.z, acc2[i][1].x);
        acc2[i][1].y = fmaf(xv2.y, wb0.w, acc2[i][1].y);
        acc2[i][2].x = fmaf(xv2.y, wb1.x, acc2[i][2].x);
        acc2[i][2].y = fmaf(xv2.y, wb1.y, acc2[i][2].y);
        acc2[i][3].x = fmaf(xv2.y, wb1.z, acc2[i][3].x);
        acc2[i][3].y = fmaf(xv2.y, wb1.w, acc2[i][3].y);
      }
    }
    __syncthreads();
  }
  float bv[8];
#pragma unroll
  for (int j = 0; j < 8; ++j) bv[j] = bias[ubase + j];
#pragma unroll
  for (int i = 0; i < 2; ++i) {
    const long row = row0 + tr + 64 * i;
    float4 o0, o1;
    o0.x = acc2[i][0].x + bv[0]; o0.y = acc2[i][0].y + bv[1];
    o0.z = acc2[i][1].x + bv[2]; o0.w = acc2[i][1].y + bv[3];
    o1.x = acc2[i][2].x + bv[4]; o1.y = acc2[i][2].y + bv[5];
    o1.z = acc2[i][3].x + bv[6]; o1.w = acc2[i][3].y + bv[7];
    *(float4*)(out + row * UU + ubase) = o0;
    *(float4*)(out + row * UU + ubase + 4) = o1;
  }
}

// ======================= K2 common machinery (R7-verified) ==================

#define ROTF(S) \
  __int_as_float(__builtin_amdgcn_update_dpp(0, __float_as_int(P), 0x120 + (S), 0xF, 0xF, true))

#define K2_TREE                                                              \
    const float c0 = P + tvS[0];                                             \
    const float c1 = ROTF(1) + tvS[1];                                       \
    const float c2 = ROTF(2) + tvS[2];                                       \
    const float c3 = ROTF(3) + tvS[3];                                       \
    const float c4 = ROTF(4) + tvS[4];                                       \
    const float c5 = ROTF(5) + tvS[5];                                       \
    const float c6 = ROTF(6) + tvS[6];                                       \
    const float c7 = ROTF(7) + tvS[7];                                       \
    const float c8 = ROTF(8) + tvS[8];                                       \
    const float c9 = ROTF(9) + tvS[9];                                       \
    const float c10 = ROTF(10) + tvS[10];                                    \
    const float c11 = ROTF(11) + tvS[11];                                    \
    const float c12 = ROTF(12) + tvS[12];                                    \
    const float c13 = ROTF(13) + tvS[13];                                    \
    const float c14 = ROTF(14) + tvS[14];                                    \
    const float c15 = ROTF(15) + tvS[15];                                    \
    const float d0 = fmaxf(fmaxf(c0, c1), c2);                               \
    const float d1 = fmaxf(fmaxf(c3, c4), c5);                               \
    const float d2 = fmaxf(fmaxf(c6, c7), c8);                               \
    const float d3 = fmaxf(fmaxf(c9, c10), c11);                             \
    const float d4 = fmaxf(fmaxf(c12, c13), c14);                            \
    const float e0 = fmaxf(fmaxf(d0, d1), d2);                               \
    const float e1 = fmaxf(fmaxf(d3, d4), c15);                              \
    const float pm = fmaxf(e0, e1);

#if __has_builtin(__builtin_amdgcn_permlane32_swap) && __has_builtin(__builtin_amdgcn_permlane16_swap)
#define K2_HAVE_PERMLANE 1
typedef unsigned int v2u __attribute__((ext_vector_type(2)));

#define K2_FSTEP(tval, lg) do {                                              \
    K2_TREE                                                                  \
    v2u s32 = __builtin_amdgcn_permlane32_swap(__float_as_uint(pm),          \
                                               __float_as_uint(pm), false, false); \
    const float pd = fmaxf(__uint_as_float(s32.x), __uint_as_float(s32.y)) + (lg); \
    v2u s16 = __builtin_amdgcn_permlane16_swap(__float_as_uint(pd),          \
                                               __float_as_uint(pd), false, false); \
    const float cx = m16sel ? __uint_as_float(s16.x) : __uint_as_float(s16.y); \
    P = bit5v ? cx : pd;                                                     \
    base[(size_t)(tval) * UU + cstoS] = P;                                   \
  } while (0)

// combined pre-logit max (bitwise-identical tree + swap32 fold of K2_FSTEP)
__device__ __forceinline__ float k2_mcomb(float P, const float* tvS) {
  K2_TREE
  v2u s32 = __builtin_amdgcn_permlane32_swap(__float_as_uint(pm),
                                             __float_as_uint(pm), false, false);
  return fmaxf(__uint_as_float(s32.x), __uint_as_float(s32.y));
}
#endif

// ---------------------------------------------------------------------------
// K2a: S=4 speculation. 256 blocks = 4 roles x 64 chains.
//  role 0: TRUE rows 1..512 from alpha0.
//  role j=1..3: SPECULATIVE from fresh start at logits[512j+1] (junction row
//  512j+1 untouched), rows 512j+2 .. segEnd (1024/1536/2047).
// Max-plus shift invariance: spec differs from true by a per-row offset that
// becomes UNIFORM after coupling; k2b finds the 3 constants, k2c applies them
// PER SEGMENT.
// ---------------------------------------------------------------------------
__global__ __launch_bounds__(64) void k2a_forward(float* __restrict__ lb,
                                                  const float* __restrict__ trans) {
  const int lane = threadIdx.x;
  const int q = lane & 15;
  const int bit4 = (lane >> 4) & 1;
  const int bit5v = (lane >> 5) & 1;
  const int hiS = bit4 ^ bit5v;
  const int tgtS = bit4 * 16 + q;
  const int cstoS = hiS * 16 + q;
  const int role = blockIdx.x >> 6;
  const int b = blockIdx.x & 63;

  const int probe = __builtin_amdgcn_update_dpp(0, q, 0x121, 0xF, 0xF, false);
  const bool dirp = (probe == ((q + 1) & 15));

  float tvS[16];
#pragma unroll
  for (int s = 0; s < 16; ++s) {
    const int rp = dirp ? ((q + s) & 15) : ((q - s) & 15);
    tvS[s] = trans[(hiS * 16 + rp) * UU + tgtS];
  }

  float* base = lb + (size_t)b * TT * UU;
  float bufA[16], bufB[16];

#ifdef K2_HAVE_PERMLANE
  v2u p32 = __builtin_amdgcn_permlane32_swap((unsigned)lane, (unsigned)lane, false, false);
  v2u p16 = __builtin_amdgcn_permlane16_swap((unsigned)lane, (unsigned)lane, false, false);
  const bool c32ok = ((int)p32.x == (lane ^ 32)) || ((int)p32.y == (lane ^ 32));
  const bool c16ok = ((int)p16.x == (lane ^ 16)) || ((int)p16.y == (lane ^ 16));
  const bool m16sel = ((int)p16.x == (lane ^ 16));
  const bool okSwap = (__ballot(c32ok) == ~0ull) && (__ballot(c16ok) == ~0ull);

  if (okSwap) {
    if (role == 0) {
      // ---- true prefix: rows 1..512 (16 chunks of 32) ----
      float P = base[cstoS];
#pragma unroll
      for (int i = 0; i < 16; ++i) bufA[i] = base[(size_t)(1 + i) * UU + tgtS];
#pragma unroll 1
      for (int tc = 1; tc <= 481; tc += 32) {
#pragma unroll
        for (int i = 0; i < 16; ++i) bufB[i] = base[(size_t)(tc + 16 + i) * UU + tgtS];
#pragma unroll
        for (int i = 0; i < 16; ++i) K2_FSTEP(tc + i, bufA[i]);
#pragma unroll
        for (int i = 0; i < 16; ++i) bufA[i] = base[(size_t)(tc + 32 + i) * UU + tgtS];
#pragma unroll
        for (int i = 0; i < 16; ++i) K2_FSTEP(tc + 16 + i, bufB[i]);
      }
    } else {
      // ---- speculative segment: fresh start at logits[s0]; rows A..E ----
      const int s0 = 512 * role + 1;            // 513 / 1025 / 1537
      const int A = s0 + 1;
      const int E = (role < 3) ? (512 * (role + 1)) : (TT - 1);  // 1024/1536/2047
      float P = base[(size_t)s0 * UU + cstoS];
#pragma unroll
      for (int i = 0; i < 16; ++i) bufA[i] = base[(size_t)(A + i) * UU + tgtS];
#pragma unroll 1
      for (int tc = A; tc <= A + 448; tc += 32) {   // 15 chunks = 480 steps
#pragma unroll
        for (int i = 0; i < 16; ++i) bufB[i] = base[(size_t)(tc + 16 + i) * UU + tgtS];
#pragma unroll
        for (int i = 0; i < 16; ++i) K2_FSTEP(tc + i, bufA[i]);
#pragma unroll
        for (int i = 0; i < 16; ++i) bufA[i] = base[(size_t)(tc + 32 + i) * UU + tgtS];
#pragma unroll
        for (int i = 0; i < 16; ++i) K2_FSTEP(tc + 16 + i, bufB[i]);
      }
      // tail: bufA holds rows A+480..A+495; remaining rows A+496..E
      const int tailN = E - (A + 496) + 1;        // 15 / 15 / 14
#pragma unroll
      for (int i = 0; i < 16; ++i) {
        int r = A + 496 + i; if (r > E) r = E;
        bufB[i] = base[(size_t)r * UU + tgtS];
      }
#pragma unroll
      for (int i = 0; i < 16; ++i) K2_FSTEP(A + 480 + i, bufA[i]);
      for (int i = 0; i < tailN; ++i) K2_FSTEP(A + 496 + i, bufB[i]);
    }
    return;
  }
#endif

  // ---------------- fallback: R2 bpermute alternating S/D scheme, FULL chain
  // (roles 1-3 idle; k2b leaves defaults so k2c is a no-op) -----------------
  if (role != 0) return;
  {
    float tvD[16];
#pragma unroll
    for (int s = 0; s < 16; ++s) {
      const int rp = dirp ? ((q + s) & 15) : ((q - s) & 15);
      tvD[s] = trans[(bit4 * 16 + rp) * UU + cstoS];
    }
    const int idx32 = (lane ^ 32) << 2;
    const int idx48 = (lane ^ 48) << 2;
    float P = base[cstoS];

#define K2_BSTEP(tval, lg, TVHI, XIDX, SCOL) do {                            \
    const float g0 = P + (TVHI)[0];                                          \
    const float g1 = ROTF(1) + (TVHI)[1];                                    \
    const float g2 = ROTF(2) + (TVHI)[2];                                    \
    const float g3 = ROTF(3) + (TVHI)[3];                                    \
    const float g4 = ROTF(4) + (TVHI)[4];                                    \
    const float g5 = ROTF(5) + (TVHI)[5];                                    \
    const float g6 = ROTF(6) + (TVHI)[6];                                    \
    const float g7 = ROTF(7) + (TVHI)[7];                                    \
    const float g8 = ROTF(8) + (TVHI)[8];                                    \
    const float g9 = ROTF(9) + (TVHI)[9];                                    \
    const float g10 = ROTF(10) + (TVHI)[10];                                 \
    const float g11 = ROTF(11) + (TVHI)[11];                                 \
    const float g12 = ROTF(12) + (TVHI)[12];                                 \
    const float g13 = ROTF(13) + (TVHI)[13];                                 \
    const float g14 = ROTF(14) + (TVHI)[14];                                 \
    const float g15 = ROTF(15) + (TVHI)[15];                                 \
    const float h0 = fmaxf(fmaxf(g0, g1), g2);                               \
    const float h1 = fmaxf(fmaxf(g3, g4), g5);                               \
    const float h2 = fmaxf(fmaxf(g6, g7), g8);                               \
    const float h3 = fmaxf(fmaxf(g9, g10), g11);                             \
    const float h4 = fmaxf(fmaxf(g12, g13), g14);                            \
    const float k0 = fmaxf(fmaxf(h0, h1), h2);                               \
    const float k1 = fmaxf(fmaxf(h3, h4), g15);                              \
    const float pm2 = fmaxf(k0, k1);                                         \
    const int po = __builtin_amdgcn_ds_bpermute((XIDX), __float_as_int(pm2));\
    P = fmaxf(pm2, __int_as_float(po)) + (lg);                               \
    base[(size_t)(tval) * UU + (SCOL)] = P;                                  \
  } while (0)

#pragma unroll
    for (int i = 0; i < 16; ++i)
      bufA[i] = base[(size_t)(1 + i) * UU + ((i & 1) ? cstoS : tgtS)];
#pragma unroll 1
    for (int tc = 1; tc <= 1985; tc += 32) {
#pragma unroll
      for (int i = 0; i < 16; ++i)
        bufB[i] = base[(size_t)(tc + 16 + i) * UU + ((i & 1) ? cstoS : tgtS)];
#pragma unroll
      for (int i = 0; i < 16; ++i) {
        if ((i & 1) == 0) K2_BSTEP(tc + i, bufA[i], tvS, idx32, tgtS);
        else              K2_BSTEP(tc + i, bufA[i], tvD, idx48, cstoS);
      }
#pragma unroll
      for (int i = 0; i < 16; ++i)
        bufA[i] = base[(size_t)(tc + 32 + i) * UU + ((i & 1) ? cstoS : tgtS)];
#pragma unroll
      for (int i = 0; i < 16; ++i) {
        if ((i & 1) == 0) K2_BSTEP(tc + 16 + i, bufB[i], tvS, idx32, tgtS);
        else              K2_BSTEP(tc + 16 + i, bufB[i], tvD, idx48, cstoS);
      }
    }
#pragma unroll
    for (int i = 0; i < 16; ++i) {
      int r = 2033 + i; if (r > TT - 1) r = TT - 1;
      bufB[i] = base[(size_t)r * UU + ((i & 1) ? cstoS : tgtS)];
    }
#pragma unroll
    for (int i = 0; i < 16; ++i) {
      if ((i & 1) == 0) K2_BSTEP(2017 + i, bufA[i], tvS, idx32, tgtS);
      else              K2_BSTEP(2017 + i, bufA[i], tvD, idx48, cstoS);
    }
#pragma unroll
    for (int i = 0; i < 15; ++i) {
      if ((i & 1) == 0) K2_BSTEP(2033 + i, bufB[i], tvS, idx32, tgtS);
      else              K2_BSTEP(2033 + i, bufB[i], tvD, idx48, cstoS);
    }
  }
}

// ---------------------------------------------------------------------------
// K2b: sequential 3-junction fixup, 64 waves (one per chain). Per junction j
// (rows 513/1025/1537): step the untouched logits row with the verified
// K2_FSTEP, then d-scan that segment's spec rows: d = M(true)-M(spec) (logit
// cancels), rewrite row as spec+d (== true), stop when d is lane-uniform ->
// record (t*_j, c_j); jump true boundary to spec(segEnd)+c_j. Non-coupling
// case degrades gracefully: scan rewrites the whole segment true, c_j = 0.
// ---------------------------------------------------------------------------
__global__ __launch_bounds__(64) void k2b_fixup(float* __restrict__ lb,
                                                const float* __restrict__ trans) {
  const int lane = threadIdx.x;
  const int b = blockIdx.x;
  const int q = lane & 15;
  const int bit4 = (lane >> 4) & 1;
  const int bit5v = (lane >> 5) & 1;
  const int hiS = bit4 ^ bit5v;
  const int tgtS = bit4 * 16 + q;
  const int cstoS = hiS * 16 + q;

  const int probe = __builtin_amdgcn_update_dpp(0, q, 0x121, 0xF, 0xF, false);
  const bool dirp = (probe == ((q + 1) & 15));

  float tvS[16];
#pragma unroll
  for (int s = 0; s < 16; ++s) {
    const int rp = dirp ? ((q + s) & 15) : ((q - s) & 15);
    tvS[s] = trans[(hiS * 16 + rp) * UU + tgtS];
  }

#ifdef K2_HAVE_PERMLANE
  v2u p32 = __builtin_amdgcn_permlane32_swap((unsigned)lane, (unsigned)lane, false, false);
  v2u p16 = __builtin_amdgcn_permlane16_swap((unsigned)lane, (unsigned)lane, false, false);
  const bool c32ok = ((int)p32.x == (lane ^ 32)) || ((int)p32.y == (lane ^ 32));
  const bool c16ok = ((int)p16.x == (lane ^ 16)) || ((int)p16.y == (lane ^ 16));
  const bool m16sel = ((int)p16.x == (lane ^ 16));
  const bool okSwap = (__ballot(c32ok) == ~0ull) && (__ballot(c16ok) == ~0ull);
  if (!okSwap) {
    if (lane == 0) {
#pragma unroll
      for (int j = 0; j < 3; ++j) { g_ts[b * 3 + j] = (j < 2) ? (1024 + 512 * j) : (TT - 1); g_c[b * 3 + j] = 0.0f; }
    }
    return;  // fallback path already computed the full true chain
  }

  float* base = lb + (size_t)b * TT * UU;
  const float TAU = 0.05f;
  float trueP = base[(size_t)512 * UU + cstoS];   // true (role-0 output)

#pragma unroll 1
  for (int j = 0; j < 3; ++j) {
    const int jr = 513 + 512 * j;                       // junction row (logits)
    const int segEnd = (j < 2) ? (1024 + 512 * j) : (TT - 1);
    const float specInit = base[(size_t)jr * UU + cstoS];  // read BEFORE store
    const float lgj = base[(size_t)jr * UU + tgtS];
    { float P = trueP; K2_FSTEP(jr, lgj); trueP = P; }   // row jr now true
    float specP = specInit;

    float ring[4];
#pragma unroll
    for (int i = 0; i < 4; ++i) {
      int r = jr + 1 + i; if (r > segEnd) r = segEnd;
      ring[i] = base[(size_t)r * UU + cstoS];
    }
    int ts_rec = segEnd; float c_rec = 0.0f;
#pragma unroll 1
    for (int t = jr + 1; t <= segEnd; ++t) {
      const float specRow = ring[(t - (jr + 1)) & 3];
      const int pf = t + 4;
      if (pf <= segEnd) ring[(t - (jr + 1)) & 3] = base[(size_t)pf * UU + cstoS];
      const float Mt = k2_mcomb(trueP, tvS);
      const float Ms = k2_mcomb(specP, tvS);
      const float d = Mt - Ms;
      v2u s16d = __builtin_amdgcn_permlane16_swap(__float_as_uint(d),
                                                  __float_as_uint(d), false, false);
      const float dx = m16sel ? __uint_as_float(s16d.x) : __uint_as_float(s16d.y);
      const float dsel = bit5v ? dx : d;
      const float nt = specRow + dsel;
      base[(size_t)t * UU + cstoS] = nt;
      const float dref = __uint_as_float(
          (unsigned)__builtin_amdgcn_readfirstlane(__float_as_int(d)));
      const bool uni = (__ballot(fabsf(d - dref) <= TAU) == ~0ull);
      trueP = nt;
      specP = specRow;
      if (uni) { ts_rec = t; c_rec = dref; break; }
    }
    if (lane == 0) { g_ts[b * 3 + j] = ts_rec; g_c[b * 3 + j] = c_rec; }
    if (ts_rec < segEnd) {
      // early couple: true(segEnd) = spec(segEnd) + c (uniform scalar)
      trueP = base[(size_t)segEnd * UU + cstoS] + c_rec;
    }  // else trueP already holds the true boundary value
  }
#else
  if (lane == 0) {
#pragma unroll
    for (int j = 0; j < 3; ++j) { g_ts[b * 3 + j] = (j < 2) ? (1024 + 512 * j) : (TT - 1); g_c[b * 3 + j] = 0.0f; }
  }
#endif
}

// ---------------------------------------------------------------------------
// K2c: apply PER-SEGMENT offsets: rows (ts_j, segEnd_j] += c_j. Rows the
// k2b scan rewrote (jr..ts_j) are already true and get nothing; later
// segments have their OWN independent constants (each spec starts fresh).
// ---------------------------------------------------------------------------
__global__ __launch_bounds__(256) void k2c_apply(float* __restrict__ lb) {
  const int b = blockIdx.x;
#pragma unroll 1
  for (int j = 0; j < 3; ++j) {
    const int ts = g_ts[b * 3 + j];
    const int segEnd = (j < 2) ? (1024 + 512 * j) : (TT - 1);
    const float c = g_c[b * 3 + j];
    if (c == 0.0f || ts >= segEnd) continue;
    const int r0 = ts + 1;
    float4* p = (float4*)(lb + ((size_t)b * TT + r0) * UU);
    const int n4 = (segEnd - r0 + 1) * (UU / 4);
    for (int i = threadIdx.x; i < n4; i += 256) {
      float4 v = p[i];
      v.x += c; v.y += c; v.z += c; v.w += c;
      p[i] = v;
    }
  }
}

// ---------------------------------------------------------------------------
// K3: backpointers, fully parallel from stored alpha rows.  (unchanged)
// ---------------------------------------------------------------------------
__global__ __launch_bounds__(256) void k3_bp(const float* __restrict__ lb,
                                             const float* __restrict__ trans,
                                             const int* __restrict__ nwords,
                                             unsigned char* __restrict__ bp) {
  __shared__ float as[129 * 32];
  __shared__ float ts[32 * 32];
  const int b = blockIdx.x >> 4;
  const int c = blockIdx.x & 15;
  const int t0 = 128 * c;
  const int tid = threadIdx.x;
  const float* base = lb + (size_t)b * TT * UU;
  const int nw = nwords[b];

  for (int idx = tid; idx < 129 * 32; idx += 256) {
    const int gidx = (t0 - 1) * 32 + idx;
    as[idx] = (gidx >= 0 && gidx < TT * UU) ? base[gidx] : 0.0f;
  }
  for (int idx = tid; idx < 1024; idx += 256) ts[idx] = trans[idx];
  __syncthreads();

  const int u = tid & 31;
  const int tg = tid >> 5;
  unsigned char* bpu = bp + ((size_t)b * 32 + u) * TT;

#pragma unroll 1
  for (int qq = 0; qq < 4; ++qq) {
    const int tl0 = tg * 16 + qq * 4;
    unsigned int pack = 0;
#pragma unroll
    for (int e = 0; e < 4; ++e) {
      const int tl = tl0 + e;
      const int t = t0 + tl;
      int idx;
      if (t >= 1 && t < nw) {
        float m = as[tl * 32 + 0] + ts[0 * 32 + u];
        idx = 0;
#pragma unroll
        for (int v = 1; v < 32; ++v) {
          const float cv = as[tl * 32 + v] + ts[v * 32 + u];
          if (cv > m) { m = cv; idx = v; }
        }
      } else {
        idx = u;
      }
      pack |= ((unsigned int)idx) << (8 * e);
    }
    *(unsigned int*)(bpu + t0 + tl0) = pack;
  }
}

// ---------------------------------------------------------------------------
// K4: backtrace + best_score. One wave per chain.  (R7 guard-split version)
// ---------------------------------------------------------------------------
__global__ __launch_bounds__(64) void k4_backtrace(const float* __restrict__ lb,
                                                   const unsigned char* __restrict__ bp,
                                                   const int* __restrict__ nwords,
                                                   int* __restrict__ pred,
                                                   float* __restrict__ score) {
  const int b = blockIdx.x;
  const int lane = threadIdx.x;
  const int u = lane & 31;
  const int h = lane >> 5;
  const int nw = nwords[b];

  const float a = lb[((size_t)b * TT + (nw - 1)) * UU + u];
  float m = a;
#pragma unroll
  for (int s = 32; s; s >>= 1) m = fmaxf(m, __shfl_xor(m, s));
  if (lane == 0) score[b] = m;
  const unsigned long long mask = __ballot(lane < 32 && a == m);
  int tag = __ffsll((unsigned long long)mask) - 1;
  tag = __builtin_amdgcn_readfirstlane(tag);

  int* predb = pred + b * TT;
  for (int p = nw - 1 + lane; p < TT; p += 64) predb[p] = tag;
  if (nw < 2) return;

  const unsigned char* bpb = bp + (size_t)b * 32 * TT;
  const int pcmax = (nw - 2) >> 6;
  const int thi_top = nw - 1;

  int wprev0 = 0;
  {
    const int toff = (pcmax + 1) * 64;
    if (toff < TT) wprev0 = *(const int*)(bpb + (size_t)u * TT + toff);
  }

  for (int pc = pcmax; pc >= 0; --pc) {
    int wreg[8];
#pragma unroll
    for (int j = 0; j < 8; ++j)
      wreg[j] = *(const int*)(bpb + (size_t)u * TT + pc * 64 + 4 * (h * 8 + j));
    int predv = 0;

    if (pc == pcmax) {
      const int thi = thi_top;
      if (pc * 64 + 64 <= thi) {
        const int val = __builtin_amdgcn_readlane(wprev0, tag);
        tag = __builtin_amdgcn_readfirstlane(val & 0xFF);
        if (lane == 63) predv = tag;
      }
#pragma unroll
      for (int lt = 63; lt >= 1; --lt) {
        if (pc * 64 + lt <= thi) {
          const int d = lt >> 2, byte = lt & 3;
          const int hs = d >> 3, j = d & 7;
          const int val = __builtin_amdgcn_readlane(wreg[j], hs * 32 + tag);
          tag = __builtin_amdgcn_readfirstlane((val >> (8 * byte)) & 0xFF);
          if (lane == lt - 1) predv = tag;
        }
      }
      const int lim = thi - pc * 64;
      if (lane < lim) predb[pc * 64 + lane] = predv;
    } else {
      {
        const int val = __builtin_amdgcn_readlane(wprev0, tag);
        tag = __builtin_amdgcn_readfirstlane(val & 0xFF);
        if (lane == 63) predv = tag;
      }
#pragma unroll
      for (int lt = 63; lt >= 1; --lt) {
        const int d = lt >> 2, byte = lt & 3;
        const int hs = d >> 3, j = d & 7;
        const int val = __builtin_amdgcn_readlane(wreg[j], hs * 32 + tag);
        tag = __builtin_amdgcn_readfirstlane((val >> (8 * byte)) & 0xFF);
        if (lane == lt - 1) predv = tag;
      }
      predb[pc * 64 + lane] = predv;
    }
    wprev0 = wreg[0];
  }
}

// ---------------------------------------------------------------------------
extern "C" void kernel_launch(void* const* d_in, const int* in_sizes, int n_in,
                              void* d_out, int out_size, void* d_ws, size_t ws_size,
                              hipStream_t stream) {
  const float* x = (const float*)d_in[0];
  const int* nwords = (const int*)d_in[1];
  const float* kern = (const float*)d_in[2];
  const float* chain = (const float*)d_in[3];
  const float* bias = (const float*)d_in[4];

  float* logits = (float*)d_ws;                                        // 16 MB
  unsigned char* bp = (unsigned char*)d_ws + (size_t)BB * TT * UU * 4; // +4 MB

  int* pred = (int*)d_out;
  float* score = (float*)d_out + (size_t)BB * TT;

  k1_logits<<<dim3(1024), dim3(256), 0, stream>>>(x, kern, bias, logits);
  k2a_forward<<<dim3(256), dim3(64), 0, stream>>>(logits, chain);
  k2b_fixup<<<dim3(BB), dim3(64), 0, stream>>>(logits, chain);
  k2c_apply<<<dim3(BB), dim3(256), 0, stream>>>(logits);
  k3_bp<<<dim3(BB * 16), dim3(256), 0, stream>>>(logits, chain, nwords, bp);
  k4_backtrace<<<dim3(BB), dim3(64), 0, stream>>>(logits, bp, nwords, pred, score);
}

// Round 14
// 192.244 us; speedup vs baseline: 1.9812x; 1.0920x over previous
//
#include <hip/hip_runtime.h>

#define BB 64
#define TT 2048
#define DD 512
#define UU 32

// S=8 speculation bookkeeping. Junction j (1..7) at row 256j+1.
// g_ts/g_c: per-(chain, junction) scan results. g_bound: boundary alpha/spec
// vectors saved by k2a (slot j = value at row 256(j+1) for role j; slot 0 =
// TRUE alpha at row 256), so parallel scans never race on rewritten rows.
// Cumulative algebra: C_0=0, C_j=C_{j-1}+c'_j; scan-rewritten rows [jr,ts_j]
// hold true-C_{j-1}; coupled rows (ts_j,E_j] hold spec = true-C_j.
__device__ int g_ts[BB * 7];
__device__ float g_c[BB * 7];
__device__ float g_bound[BB * 8 * 64];

// ---------------------------------------------------------------------------
// K1: logits[b,t,u] = sum_k x[b,t,k]*kernel[k,u] + bias[u]  (R7-verified)
// ---------------------------------------------------------------------------
__global__ __launch_bounds__(256, 4) void k1_logits(const float* __restrict__ x,
                                                    const float* __restrict__ w,
                                                    const float* __restrict__ bias,
                                                    float* __restrict__ out) {
  __shared__ float xs[128 * 34];
  __shared__ float wsh[32 * 36];
  const int tid = threadIdx.x;
  const long row0 = (long)blockIdx.x * 128;
  const int tr = tid >> 2;          // 0..63
  const int tc = tid & 3;
  const int ubase = tc * 8;
  const int sr = tid >> 3;          // 0..31
  const int sc = (tid & 7) * 4;

  float2 acc2[2][4];
#pragma unroll
  for (int i = 0; i < 2; ++i)
#pragma unroll
    for (int j = 0; j < 4; ++j) acc2[i][j] = make_float2(0.0f, 0.0f);

  for (int kc = 0; kc < DD; kc += 32) {
#pragma unroll
    for (int p = 0; p < 4; ++p) {
      const int r = p * 32 + sr;
      const float4 v = *(const float4*)(x + (row0 + r) * DD + kc + sc);
      *(float2*)(&xs[r * 34 + sc]) = make_float2(v.x, v.y);
      *(float2*)(&xs[r * 34 + sc + 2]) = make_float2(v.z, v.w);
    }
    {
      const int k = tid >> 3;
      const int uu4 = (tid & 7) * 4;
      const float4 v = *(const float4*)(w + (size_t)(kc + k) * UU + uu4);
      *(float4*)(&wsh[k * 36 + uu4]) = v;
    }
    __syncthreads();
#pragma unroll
    for (int kp = 0; kp < 16; ++kp) {
      const int k = kp * 2;
      const float4 wa0 = *(const float4*)(&wsh[k * 36 + ubase]);
      const float4 wa1 = *(const float4*)(&wsh[k * 36 + ubase + 4]);
      const float4 wb0 = *(const float4*)(&wsh[(k + 1) * 36 + ubase]);
      const float4 wb1 = *(const float4*)(&wsh[(k + 1) * 36 + ubase + 4]);
#pragma unroll
      for (int i = 0; i < 2; ++i) {
        const float2 xv2 = *(const float2*)(&xs[(tr + 64 * i) * 34 + k]);
        acc2[i][0].x = fmaf(xv2.x, wa0.x, acc2[i][0].x);
        acc2[i][0].y = fmaf(xv2.x, wa0.y, acc2[i][0].y);
        acc2[i][1].x = fmaf(xv2.x, wa0.z, acc2[i][1].x);
        acc2[i][1].y = fmaf(xv2.x, wa0.w, acc2[i][1].y);
        acc2[i][2].x = fmaf(xv2.x, wa1.x, acc2[i][2].x);
        acc2[i][2].y = fmaf(xv2.x, wa1.y, acc2[i][2].y);
        acc2[i][3].x = fmaf(xv2.x, wa1.z, acc2[i][3].x);
        acc2[i][3].y = fmaf(xv2.x, wa1.w, acc2[i][3].y);
        acc2[i][0].x = fmaf(xv2.y, wb0.x, acc2[i][0].x);
        acc2[i][0].y = fmaf(xv2.y, wb0.y, acc2[i][0].y);
        acc2[i][1].x = fmaf(xv2.y, wb0.z, acc2[i][1].x);
        acc2[i][1].y = fmaf(xv2.y, wb0.w, acc2[i][1].y);
        acc2[i][2].x = fmaf(xv2.y, wb1.x, acc2[i][2].x);
        acc2[i][2].y = fmaf(xv2.y, wb1.y, acc2[i][2].y);
        acc2[i][3].x = fmaf(xv2.y, wb1.z, acc2[i][3].x);
        acc2[i][3].y = fmaf(xv2.y, wb1.w, acc2[i][3].y);
      }
    }
    __syncthreads();
  }
  float bv[8];
#pragma unroll
  for (int j = 0; j < 8; ++j) bv[j] = bias[ubase + j];
#pragma unroll
  for (int i = 0; i < 2; ++i) {
    const long row = row0 + tr + 64 * i;
    float4 o0, o1;
    o0.x = acc2[i][0].x + bv[0]; o0.y = acc2[i][0].y + bv[1];
    o0.z = acc2[i][1].x + bv[2]; o0.w = acc2[i][1].y + bv[3];
    o1.x = acc2[i][2].x + bv[4]; o1.y = acc2[i][2].y + bv[5];
    o1.z = acc2[i][3].x + bv[6]; o1.w = acc2[i][3].y + bv[7];
    *(float4*)(out + row * UU + ubase) = o0;
    *(float4*)(out + row * UU + ubase + 4) = o1;
  }
}

// ======================= K2 common machinery (R7-verified) ==================

#define ROTF(S) \
  __int_as_float(__builtin_amdgcn_update_dpp(0, __float_as_int(P), 0x120 + (S), 0xF, 0xF, true))

#define K2_TREE                                                              \
    const float c0 = P + tvS[0];                                             \
    const float c1 = ROTF(1) + tvS[1];                                       \
    const float c2 = ROTF(2) + tvS[2];                                       \
    const float c3 = ROTF(3) + tvS[3];                                       \
    const float c4 = ROTF(4) + tvS[4];                                       \
    const float c5 = ROTF(5) + tvS[5];                                       \
    const float c6 = ROTF(6) + tvS[6];                                       \
    const float c7 = ROTF(7) + tvS[7];                                       \
    const float c8 = ROTF(8) + tvS[8];                                       \
    const float c9 = ROTF(9) + tvS[9];                                       \
    const float c10 = ROTF(10) + tvS[10];                                    \
    const float c11 = ROTF(11) + tvS[11];                                    \
    const float c12 = ROTF(12) + tvS[12];                                    \
    const float c13 = ROTF(13) + tvS[13];                                    \
    const float c14 = ROTF(14) + tvS[14];                                    \
    const float c15 = ROTF(15) + tvS[15];                                    \
    const float d0 = fmaxf(fmaxf(c0, c1), c2);                               \
    const float d1 = fmaxf(fmaxf(c3, c4), c5);                               \
    const float d2 = fmaxf(fmaxf(c6, c7), c8);                               \
    const float d3 = fmaxf(fmaxf(c9, c10), c11);                             \
    const float d4 = fmaxf(fmaxf(c12, c13), c14);                            \
    const float e0 = fmaxf(fmaxf(d0, d1), d2);                               \
    const float e1 = fmaxf(fmaxf(d3, d4), c15);                              \
    const float pm = fmaxf(e0, e1);

#if __has_builtin(__builtin_amdgcn_permlane32_swap) && __has_builtin(__builtin_amdgcn_permlane16_swap)
#define K2_HAVE_PERMLANE 1
typedef unsigned int v2u __attribute__((ext_vector_type(2)));

#define K2_FSTEP(tval, lg) do {                                              \
    K2_TREE                                                                  \
    v2u s32 = __builtin_amdgcn_permlane32_swap(__float_as_uint(pm),          \
                                               __float_as_uint(pm), false, false); \
    const float pd = fmaxf(__uint_as_float(s32.x), __uint_as_float(s32.y)) + (lg); \
    v2u s16 = __builtin_amdgcn_permlane16_swap(__float_as_uint(pd),          \
                                               __float_as_uint(pd), false, false); \
    const float cx = m16sel ? __uint_as_float(s16.x) : __uint_as_float(s16.y); \
    P = bit5v ? cx : pd;                                                     \
    base[(size_t)(tval) * UU + cstoS] = P;                                   \
  } while (0)

// combined pre-logit max (bitwise-identical tree + swap32 fold of K2_FSTEP)
__device__ __forceinline__ float k2_mcomb(float P, const float* tvS) {
  K2_TREE
  v2u s32 = __builtin_amdgcn_permlane32_swap(__float_as_uint(pm),
                                             __float_as_uint(pm), false, false);
  return fmaxf(__uint_as_float(s32.x), __uint_as_float(s32.y));
}

// generic segment runner: steps rows [A_,E_] with live P (clamped prefetch,
// no reads beyond E_ -> no cross-role races in k2a).
#define K2_RUNSEG(A_, E_) do {                                               \
    int tcc = (A_);                                                          \
    _Pragma("unroll")                                                        \
    for (int i = 0; i < 16; ++i) {                                           \
      int r = (A_) + i; if (r > (E_)) r = (E_);                              \
      bufA[i] = base[(size_t)r * UU + tgtS];                                 \
    }                                                                        \
    _Pragma("unroll 1")                                                      \
    for (; tcc + 31 <= (E_); tcc += 32) {                                    \
      _Pragma("unroll")                                                      \
      for (int i = 0; i < 16; ++i) bufB[i] = base[(size_t)(tcc + 16 + i) * UU + tgtS]; \
      _Pragma("unroll")                                                      \
      for (int i = 0; i < 16; ++i) K2_FSTEP(tcc + i, bufA[i]);               \
      _Pragma("unroll")                                                      \
      for (int i = 0; i < 16; ++i) {                                         \
        int r = tcc + 32 + i; if (r > (E_)) r = (E_);                        \
        bufA[i] = base[(size_t)r * UU + tgtS];                               \
      }                                                                      \
      _Pragma("unroll")                                                      \
      for (int i = 0; i < 16; ++i) K2_FSTEP(tcc + 16 + i, bufB[i]);          \
    }                                                                        \
    const int rem = (E_) - tcc + 1;                                          \
    if (rem > 0) {                                                           \
      _Pragma("unroll")                                                      \
      for (int i = 0; i < 16; ++i) {                                         \
        int r = tcc + 16 + i; if (r > (E_)) r = (E_);                        \
        bufB[i] = base[(size_t)r * UU + tgtS];                               \
      }                                                                      \
      _Pragma("unroll")                                                      \
      for (int i = 0; i < 16; ++i) { if (i < rem) K2_FSTEP(tcc + i, bufA[i]); } \
      _Pragma("unroll")                                                      \
      for (int i = 0; i < 16; ++i) { if (16 + i < rem) K2_FSTEP(tcc + 16 + i, bufB[i]); } \
    }                                                                        \
  } while (0)
#endif

// ---------------------------------------------------------------------------
// K2a: S=8 speculation. 512 blocks = 8 roles x 64 chains.
//  role 0: TRUE rows 1..256 from alpha0; saves boundary vector to g_bound[0].
//  role j=1..7: SPECULATIVE from fresh start at logits[256j+1] (junction row
//  untouched), rows 256j+2..E_j (E_j = 256(j+1), E_7 = 2047); saves its final
//  boundary vector to g_bound[j].
// ---------------------------------------------------------------------------
__global__ __launch_bounds__(64) void k2a_forward(float* __restrict__ lb,
                                                  const float* __restrict__ trans) {
  const int lane = threadIdx.x;
  const int q = lane & 15;
  const int bit4 = (lane >> 4) & 1;
  const int bit5v = (lane >> 5) & 1;
  const int hiS = bit4 ^ bit5v;
  const int tgtS = bit4 * 16 + q;
  const int cstoS = hiS * 16 + q;
  const int role = blockIdx.x >> 6;
  const int b = blockIdx.x & 63;

  const int probe = __builtin_amdgcn_update_dpp(0, q, 0x121, 0xF, 0xF, false);
  const bool dirp = (probe == ((q + 1) & 15));

  float tvS[16];
#pragma unroll
  for (int s = 0; s < 16; ++s) {
    const int rp = dirp ? ((q + s) & 15) : ((q - s) & 15);
    tvS[s] = trans[(hiS * 16 + rp) * UU + tgtS];
  }

  float* base = lb + (size_t)b * TT * UU;
  float bufA[16], bufB[16];

#ifdef K2_HAVE_PERMLANE
  v2u p32 = __builtin_amdgcn_permlane32_swap((unsigned)lane, (unsigned)lane, false, false);
  v2u p16 = __builtin_amdgcn_permlane16_swap((unsigned)lane, (unsigned)lane, false, false);
  const bool c32ok = ((int)p32.x == (lane ^ 32)) || ((int)p32.y == (lane ^ 32));
  const bool c16ok = ((int)p16.x == (lane ^ 16)) || ((int)p16.y == (lane ^ 16));
  const bool m16sel = ((int)p16.x == (lane ^ 16));
  const bool okSwap = (__ballot(c32ok) == ~0ull) && (__ballot(c16ok) == ~0ull);

  if (okSwap) {
    if (role == 0) {
      float P = base[cstoS];
      K2_RUNSEG(1, 256);
      g_bound[((b << 3) + 0) * 64 + lane] = P;
    } else {
      const int s0 = 256 * role + 1;
      const int E = (role < 7) ? (256 * (role + 1)) : (TT - 1);
      float P = base[(size_t)s0 * UU + cstoS];
      K2_RUNSEG(s0 + 1, E);
      g_bound[((b << 3) + role) * 64 + lane] = P;
    }
    return;
  }
#endif

  // ---------------- fallback: R2 bpermute alternating S/D scheme, FULL chain
  // (roles 1-7 idle; k2b writes defaults so k2c is a no-op) -----------------
  if (role != 0) return;
  {
    float tvD[16];
#pragma unroll
    for (int s = 0; s < 16; ++s) {
      const int rp = dirp ? ((q + s) & 15) : ((q - s) & 15);
      tvD[s] = trans[(bit4 * 16 + rp) * UU + cstoS];
    }
    const int idx32 = (lane ^ 32) << 2;
    const int idx48 = (lane ^ 48) << 2;
    float P = base[cstoS];

#define K2_BSTEP(tval, lg, TVHI, XIDX, SCOL) do {                            \
    const float g0 = P + (TVHI)[0];                                          \
    const float g1 = ROTF(1) + (TVHI)[1];                                    \
    const float g2 = ROTF(2) + (TVHI)[2];                                    \
    const float g3 = ROTF(3) + (TVHI)[3];                                    \
    const float g4 = ROTF(4) + (TVHI)[4];                                    \
    const float g5 = ROTF(5) + (TVHI)[5];                                    \
    const float g6 = ROTF(6) + (TVHI)[6];                                    \
    const float g7 = ROTF(7) + (TVHI)[7];                                    \
    const float g8 = ROTF(8) + (TVHI)[8];                                    \
    const float g9 = ROTF(9) + (TVHI)[9];                                    \
    const float g10 = ROTF(10) + (TVHI)[10];                                 \
    const float g11 = ROTF(11) + (TVHI)[11];                                 \
    const float g12 = ROTF(12) + (TVHI)[12];                                 \
    const float g13 = ROTF(13) + (TVHI)[13];                                 \
    const float g14 = ROTF(14) + (TVHI)[14];                                 \
    const float g15 = ROTF(15) + (TVHI)[15];                                 \
    const float h0 = fmaxf(fmaxf(g0, g1), g2);                               \
    const float h1 = fmaxf(fmaxf(g3, g4), g5);                               \
    const float h2 = fmaxf(fmaxf(g6, g7), g8);                               \
    const float h3 = fmaxf(fmaxf(g9, g10), g11);                             \
    const float h4 = fmaxf(fmaxf(g12, g13), g14);                            \
    const float k0 = fmaxf(fmaxf(h0, h1), h2);                               \
    const float k1 = fmaxf(fmaxf(h3, h4), g15);                              \
    const float pm2 = fmaxf(k0, k1);                                         \
    const int po = __builtin_amdgcn_ds_bpermute((XIDX), __float_as_int(pm2));\
    P = fmaxf(pm2, __int_as_float(po)) + (lg);                               \
    base[(size_t)(tval) * UU + (SCOL)] = P;                                  \
  } while (0)

#pragma unroll
    for (int i = 0; i < 16; ++i)
      bufA[i] = base[(size_t)(1 + i) * UU + ((i & 1) ? cstoS : tgtS)];
#pragma unroll 1
    for (int tc = 1; tc <= 1985; tc += 32) {
#pragma unroll
      for (int i = 0; i < 16; ++i)
        bufB[i] = base[(size_t)(tc + 16 + i) * UU + ((i & 1) ? cstoS : tgtS)];
#pragma unroll
      for (int i = 0; i < 16; ++i) {
        if ((i & 1) == 0) K2_BSTEP(tc + i, bufA[i], tvS, idx32, tgtS);
        else              K2_BSTEP(tc + i, bufA[i], tvD, idx48, cstoS);
      }
#pragma unroll
      for (int i = 0; i < 16; ++i)
        bufA[i] = base[(size_t)(tc + 32 + i) * UU + ((i & 1) ? cstoS : tgtS)];
#pragma unroll
      for (int i = 0; i < 16; ++i) {
        if ((i & 1) == 0) K2_BSTEP(tc + 16 + i, bufB[i], tvS, idx32, tgtS);
        else              K2_BSTEP(tc + 16 + i, bufB[i], tvD, idx48, cstoS);
      }
    }
#pragma unroll
    for (int i = 0; i < 16; ++i) {
      int r = 2033 + i; if (r > TT - 1) r = TT - 1;
      bufB[i] = base[(size_t)r * UU + ((i & 1) ? cstoS : tgtS)];
    }
#pragma unroll
    for (int i = 0; i < 16; ++i) {
      if ((i & 1) == 0) K2_BSTEP(2017 + i, bufA[i], tvS, idx32, tgtS);
      else              K2_BSTEP(2017 + i, bufA[i], tvD, idx48, cstoS);
    }
#pragma unroll
    for (int i = 0; i < 15; ++i) {
      if ((i & 1) == 0) K2_BSTEP(2033 + i, bufB[i], tvS, idx32, tgtS);
      else              K2_BSTEP(2033 + i, bufB[i], tvD, idx48, cstoS);
    }
  }
}

// ---------------------------------------------------------------------------
// K2b: PARALLEL junction scans — 448 blocks = 7 junctions x 64 chains, all
// independent. Scan j starts from g_bound[j-1] (previous segment's k2a
// boundary vector — racefree), steps the untouched junction row with the
// verified K2_FSTEP, then d-scans its own segment's spec rows (R13-verified
// loop, byte-identical). Coupling time = argmax-merge of the segment, so it
// is reference-independent; constants compose cumulatively in k2c.
// ---------------------------------------------------------------------------
__global__ __launch_bounds__(64) void k2b_fixup(float* __restrict__ lb,
                                                const float* __restrict__ trans) {
  const int lane = threadIdx.x;
  const int b = blockIdx.x & 63;
  const int j = (blockIdx.x >> 6) + 1;            // 1..7
  const int q = lane & 15;
  const int bit4 = (lane >> 4) & 1;
  const int bit5v = (lane >> 5) & 1;
  const int hiS = bit4 ^ bit5v;
  const int tgtS = bit4 * 16 + q;
  const int cstoS = hiS * 16 + q;
  const int jr = 256 * j + 1;
  const int segEnd = (j < 7) ? (256 * (j + 1)) : (TT - 1);

  const int probe = __builtin_amdgcn_update_dpp(0, q, 0x121, 0xF, 0xF, false);
  const bool dirp = (probe == ((q + 1) & 15));

  float tvS[16];
#pragma unroll
  for (int s = 0; s < 16; ++s) {
    const int rp = dirp ? ((q + s) & 15) : ((q - s) & 15);
    tvS[s] = trans[(hiS * 16 + rp) * UU + tgtS];
  }

#ifdef K2_HAVE_PERMLANE
  v2u p32 = __builtin_amdgcn_permlane32_swap((unsigned)lane, (unsigned)lane, false, false);
  v2u p16 = __builtin_amdgcn_permlane16_swap((unsigned)lane, (unsigned)lane, false, false);
  const bool c32ok = ((int)p32.x == (lane ^ 32)) || ((int)p32.y == (lane ^ 32));
  const bool c16ok = ((int)p16.x == (lane ^ 16)) || ((int)p16.y == (lane ^ 16));
  const bool m16sel = ((int)p16.x == (lane ^ 16));
  const bool okSwap = (__ballot(c32ok) == ~0ull) && (__ballot(c16ok) == ~0ull);
  if (!okSwap) {
    if (lane == 0) { g_ts[b * 7 + j - 1] = segEnd; g_c[b * 7 + j - 1] = 0.0f; }
    return;  // fallback path computed the full true chain already
  }

  float* base = lb + (size_t)b * TT * UU;
  const float TAU = 0.05f;

  float trueP = g_bound[((b << 3) + (j - 1)) * 64 + lane];  // prev boundary
  const float specInit = base[(size_t)jr * UU + cstoS];     // logits (pre-write)
  const float lgj = base[(size_t)jr * UU + tgtS];
  { float P = trueP; K2_FSTEP(jr, lgj); trueP = P; }        // row jr <- R_j(jr)
  float specP = specInit;

  float ring[4];
#pragma unroll
  for (int i = 0; i < 4; ++i) {
    int r = jr + 1 + i; if (r > segEnd) r = segEnd;
    ring[i] = base[(size_t)r * UU + cstoS];
  }
  int ts_rec = segEnd; float c_rec = 0.0f;
#pragma unroll 1
  for (int t = jr + 1; t <= segEnd; ++t) {
    const float specRow = ring[(t - (jr + 1)) & 3];
    const int pf = t + 4;
    if (pf <= segEnd) ring[(t - (jr + 1)) & 3] = base[(size_t)pf * UU + cstoS];
    const float Mt = k2_mcomb(trueP, tvS);
    const float Ms = k2_mcomb(specP, tvS);
    const float d = Mt - Ms;
    v2u s16d = __builtin_amdgcn_permlane16_swap(__float_as_uint(d),
                                                __float_as_uint(d), false, false);
    const float dx = m16sel ? __uint_as_float(s16d.x) : __uint_as_float(s16d.y);
    const float dsel = bit5v ? dx : d;
    const float nt = specRow + dsel;
    base[(size_t)t * UU + cstoS] = nt;
    const float dref = __uint_as_float(
        (unsigned)__builtin_amdgcn_readfirstlane(__float_as_int(d)));
    const bool uni = (__ballot(fabsf(d - dref) <= TAU) == ~0ull);
    trueP = nt;
    specP = specRow;
    if (uni) { ts_rec = t; c_rec = dref; break; }
  }
  if (lane == 0) { g_ts[b * 7 + j - 1] = ts_rec; g_c[b * 7 + j - 1] = c_rec; }
#else
  if (lane == 0) { g_ts[b * 7 + j - 1] = segEnd; g_c[b * 7 + j - 1] = 0.0f; }
#endif
}

// ---------------------------------------------------------------------------
// K2c: cumulative two-range fixup per segment. C_0=0, C_j=C_{j-1}+c'_j.
// rows [jr_j, ts_j] += C_{j-1} (scan-rewritten = true - C_{j-1});
// rows (ts_j, E_j] += C_j      (coupled spec = true - C_j).
// ---------------------------------------------------------------------------
__global__ __launch_bounds__(256) void k2c_apply(float* __restrict__ lb) {
  const int b = blockIdx.x;
  float C[8];
  C[0] = 0.0f;
#pragma unroll
  for (int j = 1; j <= 7; ++j) C[j] = C[j - 1] + g_c[b * 7 + j - 1];
#pragma unroll 1
  for (int j = 1; j <= 7; ++j) {
    const int jr = 256 * j + 1;
    const int segEnd = (j < 7) ? (256 * (j + 1)) : (TT - 1);
    const int ts = g_ts[b * 7 + j - 1];
    const float cA = C[j - 1];        // rows jr..ts
    const float cB = C[j];            // rows ts+1..segEnd
    if (cA != 0.0f) {
      float4* p = (float4*)(lb + ((size_t)b * TT + jr) * UU);
      const int n4 = (ts - jr + 1) * (UU / 4);
      for (int i = threadIdx.x; i < n4; i += 256) {
        float4 v = p[i];
        v.x += cA; v.y += cA; v.z += cA; v.w += cA;
        p[i] = v;
      }
    }
    if (cB != 0.0f && ts < segEnd) {
      float4* p = (float4*)(lb + ((size_t)b * TT + ts + 1) * UU);
      const int n4 = (segEnd - ts) * (UU / 4);
      for (int i = threadIdx.x; i < n4; i += 256) {
        float4 v = p[i];
        v.x += cB; v.y += cB; v.z += cB; v.w += cB;
        p[i] = v;
      }
    }
  }
}

// ---------------------------------------------------------------------------
// K3: backpointers, fully parallel from stored alpha rows.  (unchanged)
// ---------------------------------------------------------------------------
__global__ __launch_bounds__(256) void k3_bp(const float* __restrict__ lb,
                                             const float* __restrict__ trans,
                                             const int* __restrict__ nwords,
                                             unsigned char* __restrict__ bp) {
  __shared__ float as[129 * 32];
  __shared__ float ts[32 * 32];
  const int b = blockIdx.x >> 4;
  const int c = blockIdx.x & 15;
  const int t0 = 128 * c;
  const int tid = threadIdx.x;
  const float* base = lb + (size_t)b * TT * UU;
  const int nw = nwords[b];

  for (int idx = tid; idx < 129 * 32; idx += 256) {
    const int gidx = (t0 - 1) * 32 + idx;
    as[idx] = (gidx >= 0 && gidx < TT * UU) ? base[gidx] : 0.0f;
  }
  for (int idx = tid; idx < 1024; idx += 256) ts[idx] = trans[idx];
  __syncthreads();

  const int u = tid & 31;
  const int tg = tid >> 5;
  unsigned char* bpu = bp + ((size_t)b * 32 + u) * TT;

#pragma unroll 1
  for (int qq = 0; qq < 4; ++qq) {
    const int tl0 = tg * 16 + qq * 4;
    unsigned int pack = 0;
#pragma unroll
    for (int e = 0; e < 4; ++e) {
      const int tl = tl0 + e;
      const int t = t0 + tl;
      int idx;
      if (t >= 1 && t < nw) {
        float m = as[tl * 32 + 0] + ts[0 * 32 + u];
        idx = 0;
#pragma unroll
        for (int v = 1; v < 32; ++v) {
          const float cv = as[tl * 32 + v] + ts[v * 32 + u];
          if (cv > m) { m = cv; idx = v; }
        }
      } else {
        idx = u;
      }
      pack |= ((unsigned int)idx) << (8 * e);
    }
    *(unsigned int*)(bpu + t0 + tl0) = pack;
  }
}

// ---------------------------------------------------------------------------
// K4: backtrace + best_score. One wave per chain.  (R7 guard-split version)
// ---------------------------------------------------------------------------
__global__ __launch_bounds__(64) void k4_backtrace(const float* __restrict__ lb,
                                                   const unsigned char* __restrict__ bp,
                                                   const int* __restrict__ nwords,
                                                   int* __restrict__ pred,
                                                   float* __restrict__ score) {
  const int b = blockIdx.x;
  const int lane = threadIdx.x;
  const int u = lane & 31;
  const int h = lane >> 5;
  const int nw = nwords[b];

  const float a = lb[((size_t)b * TT + (nw - 1)) * UU + u];
  float m = a;
#pragma unroll
  for (int s = 32; s; s >>= 1) m = fmaxf(m, __shfl_xor(m, s));
  if (lane == 0) score[b] = m;
  const unsigned long long mask = __ballot(lane < 32 && a == m);
  int tag = __ffsll((unsigned long long)mask) - 1;
  tag = __builtin_amdgcn_readfirstlane(tag);

  int* predb = pred + b * TT;
  for (int p = nw - 1 + lane; p < TT; p += 64) predb[p] = tag;
  if (nw < 2) return;

  const unsigned char* bpb = bp + (size_t)b * 32 * TT;
  const int pcmax = (nw - 2) >> 6;
  const int thi_top = nw - 1;

  int wprev0 = 0;
  {
    const int toff = (pcmax + 1) * 64;
    if (toff < TT) wprev0 = *(const int*)(bpb + (size_t)u * TT + toff);
  }

  for (int pc = pcmax; pc >= 0; --pc) {
    int wreg[8];
#pragma unroll
    for (int j = 0; j < 8; ++j)
      wreg[j] = *(const int*)(bpb + (size_t)u * TT + pc * 64 + 4 * (h * 8 + j));
    int predv = 0;

    if (pc == pcmax) {
      const int thi = thi_top;
      if (pc * 64 + 64 <= thi) {
        const int val = __builtin_amdgcn_readlane(wprev0, tag);
        tag = __builtin_amdgcn_readfirstlane(val & 0xFF);
        if (lane == 63) predv = tag;
      }
#pragma unroll
      for (int lt = 63; lt >= 1; --lt) {
        if (pc * 64 + lt <= thi) {
          const int d = lt >> 2, byte = lt & 3;
          const int hs = d >> 3, j = d & 7;
          const int val = __builtin_amdgcn_readlane(wreg[j], hs * 32 + tag);
          tag = __builtin_amdgcn_readfirstlane((val >> (8 * byte)) & 0xFF);
          if (lane == lt - 1) predv = tag;
        }
      }
      const int lim = thi - pc * 64;
      if (lane < lim) predb[pc * 64 + lane] = predv;
    } else {
      {
        const int val = __builtin_amdgcn_readlane(wprev0, tag);
        tag = __builtin_amdgcn_readfirstlane(val & 0xFF);
        if (lane == 63) predv = tag;
      }
#pragma unroll
      for (int lt = 63; lt >= 1; --lt) {
        const int d = lt >> 2, byte = lt & 3;
        const int hs = d >> 3, j = d & 7;
        const int val = __builtin_amdgcn_readlane(wreg[j], hs * 32 + tag);
        tag = __builtin_amdgcn_readfirstlane((val >> (8 * byte)) & 0xFF);
        if (lane == lt - 1) predv = tag;
      }
      predb[pc * 64 + lane] = predv;
    }
    wprev0 = wreg[0];
  }
}

// ---------------------------------------------------------------------------
extern "C" void kernel_launch(void* const* d_in, const int* in_sizes, int n_in,
                              void* d_out, int out_size, void* d_ws, size_t ws_size,
                              hipStream_t stream) {
  const float* x = (const float*)d_in[0];
  const int* nwords = (const int*)d_in[1];
  const float* kern = (const float*)d_in[2];
  const float* chain = (const float*)d_in[3];
  const float* bias = (const float*)d_in[4];

  float* logits = (float*)d_ws;                                        // 16 MB
  unsigned char* bp = (unsigned char*)d_ws + (size_t)BB * TT * UU * 4; // +4 MB

  int* pred = (int*)d_out;
  float* score = (float*)d_out + (size_t)BB * TT;

  k1_logits<<<dim3(1024), dim3(256), 0, stream>>>(x, kern, bias, logits);
  k2a_forward<<<dim3(512), dim3(64), 0, stream>>>(logits, chain);
  k2b_fixup<<<dim3(448), dim3(64), 0, stream>>>(logits, chain);
  k2c_apply<<<dim3(BB), dim3(256), 0, stream>>>(logits);
  k3_bp<<<dim3(BB * 16), dim3(256), 0, stream>>>(logits, chain, nwords, bp);
  k4_backtrace<<<dim3(BB), dim3(64), 0, stream>>>(logits, bp, nwords, pred, score);
}

// Round 15
// 178.751 us; speedup vs baseline: 2.1308x; 1.0755x over previous
//
#include <hip/hip_runtime.h>

#define BB 64
#define TT 2048
#define DD 512
#define UU 32

// S=8 speculation bookkeeping. Junction j (1..7) at row 256j+1.
// g_ts/g_c: per-(chain, junction) scan results. g_bound: boundary vectors
// saved by k2a. Offsets are now applied AT READ TIME in k3/k4 (k2c removed):
// off(row): row<=256 -> 0; segment j: rows [jr, ts_j] -> C[j-1], (ts_j, E_j]
// -> C[j], with C[0]=0, C[j]=C[j-1]+c'_j. Row-uniform adds don't change
// k3's argmax; k4 adds off to its single alpha row (score exact).
__device__ int g_ts[BB * 7];
__device__ float g_c[BB * 7];
__device__ float g_bound[BB * 8 * 64];

// ---------------------------------------------------------------------------
// K1: logits GEMM. R0's verified 256-row/4-rows-per-thread geometry (halves
// the per-fma LDS W-read issue vs the 128-row shape) + R7's float2 k-pair
// x-reads. Per-accumulator fma chain is ascending-k, identical operands =>
// bit-identical logits to all prior verified versions.
// ---------------------------------------------------------------------------
__global__ __launch_bounds__(256) void k1_logits(const float* __restrict__ x,
                                                 const float* __restrict__ w,
                                                 const float* __restrict__ bias,
                                                 float* __restrict__ out) {
  __shared__ float xs[256 * 34];
  __shared__ float wsh[32 * 36];
  const int tid = threadIdx.x;
  const long row0 = (long)blockIdx.x * 256;
  const int tr = tid >> 2;
  const int tc = tid & 3;
  const int ubase = tc * 8;
  const int sr = tid >> 3;
  const int sc = (tid & 7) * 4;

  float acc[4][8];
#pragma unroll
  for (int i = 0; i < 4; ++i)
#pragma unroll
    for (int j = 0; j < 8; ++j) acc[i][j] = 0.0f;

  for (int kc = 0; kc < DD; kc += 32) {
#pragma unroll
    for (int p = 0; p < 8; ++p) {
      const int r = p * 32 + sr;
      const float4 v = *(const float4*)(x + (row0 + r) * DD + kc + sc);
      *(float2*)(&xs[r * 34 + sc]) = make_float2(v.x, v.y);
      *(float2*)(&xs[r * 34 + sc + 2]) = make_float2(v.z, v.w);
    }
    {
      const int k = tid >> 3;
      const int uu4 = (tid & 7) * 4;
      const float4 v = *(const float4*)(w + (size_t)(kc + k) * UU + uu4);
      *(float4*)(&wsh[k * 36 + uu4]) = v;
    }
    __syncthreads();
#pragma unroll
    for (int kp = 0; kp < 16; ++kp) {
      const int k = kp * 2;
      const float4 wa0 = *(const float4*)(&wsh[k * 36 + ubase]);
      const float4 wa1 = *(const float4*)(&wsh[k * 36 + ubase + 4]);
      const float4 wb0 = *(const float4*)(&wsh[(k + 1) * 36 + ubase]);
      const float4 wb1 = *(const float4*)(&wsh[(k + 1) * 36 + ubase + 4]);
      const float wva[8] = {wa0.x, wa0.y, wa0.z, wa0.w, wa1.x, wa1.y, wa1.z, wa1.w};
      const float wvb[8] = {wb0.x, wb0.y, wb0.z, wb0.w, wb1.x, wb1.y, wb1.z, wb1.w};
#pragma unroll
      for (int i = 0; i < 4; ++i) {
        const float2 xv2 = *(const float2*)(&xs[(tr + 64 * i) * 34 + k]);
#pragma unroll
        for (int j = 0; j < 8; ++j) acc[i][j] = fmaf(xv2.x, wva[j], acc[i][j]);
#pragma unroll
        for (int j = 0; j < 8; ++j) acc[i][j] = fmaf(xv2.y, wvb[j], acc[i][j]);
      }
    }
    __syncthreads();
  }
  float bv[8];
#pragma unroll
  for (int j = 0; j < 8; ++j) bv[j] = bias[ubase + j];
#pragma unroll
  for (int i = 0; i < 4; ++i) {
    const long row = row0 + tr + 64 * i;
    float4 o0, o1;
    o0.x = acc[i][0] + bv[0]; o0.y = acc[i][1] + bv[1];
    o0.z = acc[i][2] + bv[2]; o0.w = acc[i][3] + bv[3];
    o1.x = acc[i][4] + bv[4]; o1.y = acc[i][5] + bv[5];
    o1.z = acc[i][6] + bv[6]; o1.w = acc[i][7] + bv[7];
    *(float4*)(out + row * UU + ubase) = o0;
    *(float4*)(out + row * UU + ubase + 4) = o1;
  }
}

// ======================= K2 common machinery (R7-verified) ==================

#define ROTF(S) \
  __int_as_float(__builtin_amdgcn_update_dpp(0, __float_as_int(P), 0x120 + (S), 0xF, 0xF, true))

#define K2_TREE                                                              \
    const float c0 = P + tvS[0];                                             \
    const float c1 = ROTF(1) + tvS[1];                                       \
    const float c2 = ROTF(2) + tvS[2];                                       \
    const float c3 = ROTF(3) + tvS[3];                                       \
    const float c4 = ROTF(4) + tvS[4];                                       \
    const float c5 = ROTF(5) + tvS[5];                                       \
    const float c6 = ROTF(6) + tvS[6];                                       \
    const float c7 = ROTF(7) + tvS[7];                                       \
    const float c8 = ROTF(8) + tvS[8];                                       \
    const float c9 = ROTF(9) + tvS[9];                                       \
    const float c10 = ROTF(10) + tvS[10];                                    \
    const float c11 = ROTF(11) + tvS[11];                                    \
    const float c12 = ROTF(12) + tvS[12];                                    \
    const float c13 = ROTF(13) + tvS[13];                                    \
    const float c14 = ROTF(14) + tvS[14];                                    \
    const float c15 = ROTF(15) + tvS[15];                                    \
    const float d0 = fmaxf(fmaxf(c0, c1), c2);                               \
    const float d1 = fmaxf(fmaxf(c3, c4), c5);                               \
    const float d2 = fmaxf(fmaxf(c6, c7), c8);                               \
    const float d3 = fmaxf(fmaxf(c9, c10), c11);                             \
    const float d4 = fmaxf(fmaxf(c12, c13), c14);                            \
    const float e0 = fmaxf(fmaxf(d0, d1), d2);                               \
    const float e1 = fmaxf(fmaxf(d3, d4), c15);                              \
    const float pm = fmaxf(e0, e1);

#if __has_builtin(__builtin_amdgcn_permlane32_swap) && __has_builtin(__builtin_amdgcn_permlane16_swap)
#define K2_HAVE_PERMLANE 1
typedef unsigned int v2u __attribute__((ext_vector_type(2)));

#define K2_FSTEP(tval, lg) do {                                              \
    K2_TREE                                                                  \
    v2u s32 = __builtin_amdgcn_permlane32_swap(__float_as_uint(pm),          \
                                               __float_as_uint(pm), false, false); \
    const float pd = fmaxf(__uint_as_float(s32.x), __uint_as_float(s32.y)) + (lg); \
    v2u s16 = __builtin_amdgcn_permlane16_swap(__float_as_uint(pd),          \
                                               __float_as_uint(pd), false, false); \
    const float cx = m16sel ? __uint_as_float(s16.x) : __uint_as_float(s16.y); \
    P = bit5v ? cx : pd;                                                     \
    base[(size_t)(tval) * UU + cstoS] = P;                                   \
  } while (0)

// combined pre-logit max (bitwise-identical tree + swap32 fold of K2_FSTEP)
__device__ __forceinline__ float k2_mcomb(float P, const float* tvS) {
  K2_TREE
  v2u s32 = __builtin_amdgcn_permlane32_swap(__float_as_uint(pm),
                                             __float_as_uint(pm), false, false);
  return fmaxf(__uint_as_float(s32.x), __uint_as_float(s32.y));
}

// generic segment runner: steps rows [A_,E_] with live P (clamped prefetch,
// no reads beyond E_ -> no cross-role races in k2a).
#define K2_RUNSEG(A_, E_) do {                                               \
    int tcc = (A_);                                                          \
    _Pragma("unroll")                                                        \
    for (int i = 0; i < 16; ++i) {                                           \
      int r = (A_) + i; if (r > (E_)) r = (E_);                              \
      bufA[i] = base[(size_t)r * UU + tgtS];                                 \
    }                                                                        \
    _Pragma("unroll 1")                                                      \
    for (; tcc + 31 <= (E_); tcc += 32) {                                    \
      _Pragma("unroll")                                                      \
      for (int i = 0; i < 16; ++i) bufB[i] = base[(size_t)(tcc + 16 + i) * UU + tgtS]; \
      _Pragma("unroll")                                                      \
      for (int i = 0; i < 16; ++i) K2_FSTEP(tcc + i, bufA[i]);               \
      _Pragma("unroll")                                                      \
      for (int i = 0; i < 16; ++i) {                                         \
        int r = tcc + 32 + i; if (r > (E_)) r = (E_);                        \
        bufA[i] = base[(size_t)r * UU + tgtS];                               \
      }                                                                      \
      _Pragma("unroll")                                                      \
      for (int i = 0; i < 16; ++i) K2_FSTEP(tcc + 16 + i, bufB[i]);          \
    }                                                                        \
    const int rem = (E_) - tcc + 1;                                          \
    if (rem > 0) {                                                           \
      _Pragma("unroll")                                                      \
      for (int i = 0; i < 16; ++i) {                                         \
        int r = tcc + 16 + i; if (r > (E_)) r = (E_);                        \
        bufB[i] = base[(size_t)r * UU + tgtS];                               \
      }                                                                      \
      _Pragma("unroll")                                                      \
      for (int i = 0; i < 16; ++i) { if (i < rem) K2_FSTEP(tcc + i, bufA[i]); } \
      _Pragma("unroll")                                                      \
      for (int i = 0; i < 16; ++i) { if (16 + i < rem) K2_FSTEP(tcc + 16 + i, bufB[i]); } \
    }                                                                        \
  } while (0)
#endif

// ---------------------------------------------------------------------------
// K2a: S=8 speculation. 512 blocks = 8 roles x 64 chains.  (R14-verified)
// ---------------------------------------------------------------------------
__global__ __launch_bounds__(64) void k2a_forward(float* __restrict__ lb,
                                                  const float* __restrict__ trans) {
  const int lane = threadIdx.x;
  const int q = lane & 15;
  const int bit4 = (lane >> 4) & 1;
  const int bit5v = (lane >> 5) & 1;
  const int hiS = bit4 ^ bit5v;
  const int tgtS = bit4 * 16 + q;
  const int cstoS = hiS * 16 + q;
  const int role = blockIdx.x >> 6;
  const int b = blockIdx.x & 63;

  const int probe = __builtin_amdgcn_update_dpp(0, q, 0x121, 0xF, 0xF, false);
  const bool dirp = (probe == ((q + 1) & 15));

  float tvS[16];
#pragma unroll
  for (int s = 0; s < 16; ++s) {
    const int rp = dirp ? ((q + s) & 15) : ((q - s) & 15);
    tvS[s] = trans[(hiS * 16 + rp) * UU + tgtS];
  }

  float* base = lb + (size_t)b * TT * UU;
  float bufA[16], bufB[16];

#ifdef K2_HAVE_PERMLANE
  v2u p32 = __builtin_amdgcn_permlane32_swap((unsigned)lane, (unsigned)lane, false, false);
  v2u p16 = __builtin_amdgcn_permlane16_swap((unsigned)lane, (unsigned)lane, false, false);
  const bool c32ok = ((int)p32.x == (lane ^ 32)) || ((int)p32.y == (lane ^ 32));
  const bool c16ok = ((int)p16.x == (lane ^ 16)) || ((int)p16.y == (lane ^ 16));
  const bool m16sel = ((int)p16.x == (lane ^ 16));
  const bool okSwap = (__ballot(c32ok) == ~0ull) && (__ballot(c16ok) == ~0ull);

  if (okSwap) {
    if (role == 0) {
      float P = base[cstoS];
      K2_RUNSEG(1, 256);
      g_bound[((b << 3) + 0) * 64 + lane] = P;
    } else {
      const int s0 = 256 * role + 1;
      const int E = (role < 7) ? (256 * (role + 1)) : (TT - 1);
      float P = base[(size_t)s0 * UU + cstoS];
      K2_RUNSEG(s0 + 1, E);
      g_bound[((b << 3) + role) * 64 + lane] = P;
    }
    return;
  }
#endif

  // ---------------- fallback: R2 bpermute alternating S/D scheme, FULL chain
  if (role != 0) return;
  {
    float tvD[16];
#pragma unroll
    for (int s = 0; s < 16; ++s) {
      const int rp = dirp ? ((q + s) & 15) : ((q - s) & 15);
      tvD[s] = trans[(bit4 * 16 + rp) * UU + cstoS];
    }
    const int idx32 = (lane ^ 32) << 2;
    const int idx48 = (lane ^ 48) << 2;
    float P = base[cstoS];

#define K2_BSTEP(tval, lg, TVHI, XIDX, SCOL) do {                            \
    const float g0 = P + (TVHI)[0];                                          \
    const float g1 = ROTF(1) + (TVHI)[1];                                    \
    const float g2 = ROTF(2) + (TVHI)[2];                                    \
    const float g3 = ROTF(3) + (TVHI)[3];                                    \
    const float g4 = ROTF(4) + (TVHI)[4];                                    \
    const float g5 = ROTF(5) + (TVHI)[5];                                    \
    const float g6 = ROTF(6) + (TVHI)[6];                                    \
    const float g7 = ROTF(7) + (TVHI)[7];                                    \
    const float g8 = ROTF(8) + (TVHI)[8];                                    \
    const float g9 = ROTF(9) + (TVHI)[9];                                    \
    const float g10 = ROTF(10) + (TVHI)[10];                                 \
    const float g11 = ROTF(11) + (TVHI)[11];                                 \
    const float g12 = ROTF(12) + (TVHI)[12];                                 \
    const float g13 = ROTF(13) + (TVHI)[13];                                 \
    const float g14 = ROTF(14) + (TVHI)[14];                                 \
    const float g15 = ROTF(15) + (TVHI)[15];                                 \
    const float h0 = fmaxf(fmaxf(g0, g1), g2);                               \
    const float h1 = fmaxf(fmaxf(g3, g4), g5);                               \
    const float h2 = fmaxf(fmaxf(g6, g7), g8);                               \
    const float h3 = fmaxf(fmaxf(g9, g10), g11);                             \
    const float h4 = fmaxf(fmaxf(g12, g13), g14);                            \
    const float k0 = fmaxf(fmaxf(h0, h1), h2);                               \
    const float k1 = fmaxf(fmaxf(h3, h4), g15);                              \
    const float pm2 = fmaxf(k0, k1);                                         \
    const int po = __builtin_amdgcn_ds_bpermute((XIDX), __float_as_int(pm2));\
    P = fmaxf(pm2, __int_as_float(po)) + (lg);                               \
    base[(size_t)(tval) * UU + (SCOL)] = P;                                  \
  } while (0)

#pragma unroll
    for (int i = 0; i < 16; ++i)
      bufA[i] = base[(size_t)(1 + i) * UU + ((i & 1) ? cstoS : tgtS)];
#pragma unroll 1
    for (int tc = 1; tc <= 1985; tc += 32) {
#pragma unroll
      for (int i = 0; i < 16; ++i)
        bufB[i] = base[(size_t)(tc + 16 + i) * UU + ((i & 1) ? cstoS : tgtS)];
#pragma unroll
      for (int i = 0; i < 16; ++i) {
        if ((i & 1) == 0) K2_BSTEP(tc + i, bufA[i], tvS, idx32, tgtS);
        else              K2_BSTEP(tc + i, bufA[i], tvD, idx48, cstoS);
      }
#pragma unroll
      for (int i = 0; i < 16; ++i)
        bufA[i] = base[(size_t)(tc + 32 + i) * UU + ((i & 1) ? cstoS : tgtS)];
#pragma unroll
      for (int i = 0; i < 16; ++i) {
        if ((i & 1) == 0) K2_BSTEP(tc + 16 + i, bufB[i], tvS, idx32, tgtS);
        else              K2_BSTEP(tc + 16 + i, bufB[i], tvD, idx48, cstoS);
      }
    }
#pragma unroll
    for (int i = 0; i < 16; ++i) {
      int r = 2033 + i; if (r > TT - 1) r = TT - 1;
      bufB[i] = base[(size_t)r * UU + ((i & 1) ? cstoS : tgtS)];
    }
#pragma unroll
    for (int i = 0; i < 16; ++i) {
      if ((i & 1) == 0) K2_BSTEP(2017 + i, bufA[i], tvS, idx32, tgtS);
      else              K2_BSTEP(2017 + i, bufA[i], tvD, idx48, cstoS);
    }
#pragma unroll
    for (int i = 0; i < 15; ++i) {
      if ((i & 1) == 0) K2_BSTEP(2033 + i, bufB[i], tvS, idx32, tgtS);
      else              K2_BSTEP(2033 + i, bufB[i], tvD, idx48, cstoS);
    }
  }
}

// ---------------------------------------------------------------------------
// K2b: PARALLEL junction scans — 448 blocks = 7 junctions x 64 chains.
// (R14-verified, byte-identical.)
// ---------------------------------------------------------------------------
__global__ __launch_bounds__(64) void k2b_fixup(float* __restrict__ lb,
                                                const float* __restrict__ trans) {
  const int lane = threadIdx.x;
  const int b = blockIdx.x & 63;
  const int j = (blockIdx.x >> 6) + 1;            // 1..7
  const int q = lane & 15;
  const int bit4 = (lane >> 4) & 1;
  const int bit5v = (lane >> 5) & 1;
  const int hiS = bit4 ^ bit5v;
  const int tgtS = bit4 * 16 + q;
  const int cstoS = hiS * 16 + q;
  const int jr = 256 * j + 1;
  const int segEnd = (j < 7) ? (256 * (j + 1)) : (TT - 1);

  const int probe = __builtin_amdgcn_update_dpp(0, q, 0x121, 0xF, 0xF, false);
  const bool dirp = (probe == ((q + 1) & 15));

  float tvS[16];
#pragma unroll
  for (int s = 0; s < 16; ++s) {
    const int rp = dirp ? ((q + s) & 15) : ((q - s) & 15);
    tvS[s] = trans[(hiS * 16 + rp) * UU + tgtS];
  }

#ifdef K2_HAVE_PERMLANE
  v2u p32 = __builtin_amdgcn_permlane32_swap((unsigned)lane, (unsigned)lane, false, false);
  v2u p16 = __builtin_amdgcn_permlane16_swap((unsigned)lane, (unsigned)lane, false, false);
  const bool c32ok = ((int)p32.x == (lane ^ 32)) || ((int)p32.y == (lane ^ 32));
  const bool c16ok = ((int)p16.x == (lane ^ 16)) || ((int)p16.y == (lane ^ 16));
  const bool m16sel = ((int)p16.x == (lane ^ 16));
  const bool okSwap = (__ballot(c32ok) == ~0ull) && (__ballot(c16ok) == ~0ull);
  if (!okSwap) {
    if (lane == 0) { g_ts[b * 7 + j - 1] = segEnd; g_c[b * 7 + j - 1] = 0.0f; }
    return;  // fallback path computed the full true chain already
  }

  float* base = lb + (size_t)b * TT * UU;
  const float TAU = 0.05f;

  float trueP = g_bound[((b << 3) + (j - 1)) * 64 + lane];  // prev boundary
  const float specInit = base[(size_t)jr * UU + cstoS];     // logits (pre-write)
  const float lgj = base[(size_t)jr * UU + tgtS];
  { float P = trueP; K2_FSTEP(jr, lgj); trueP = P; }        // row jr <- R_j(jr)
  float specP = specInit;

  float ring[4];
#pragma unroll
  for (int i = 0; i < 4; ++i) {
    int r = jr + 1 + i; if (r > segEnd) r = segEnd;
    ring[i] = base[(size_t)r * UU + cstoS];
  }
  int ts_rec = segEnd; float c_rec = 0.0f;
#pragma unroll 1
  for (int t = jr + 1; t <= segEnd; ++t) {
    const float specRow = ring[(t - (jr + 1)) & 3];
    const int pf = t + 4;
    if (pf <= segEnd) ring[(t - (jr + 1)) & 3] = base[(size_t)pf * UU + cstoS];
    const float Mt = k2_mcomb(trueP, tvS);
    const float Ms = k2_mcomb(specP, tvS);
    const float d = Mt - Ms;
    v2u s16d = __builtin_amdgcn_permlane16_swap(__float_as_uint(d),
                                                __float_as_uint(d), false, false);
    const float dx = m16sel ? __uint_as_float(s16d.x) : __uint_as_float(s16d.y);
    const float dsel = bit5v ? dx : d;
    const float nt = specRow + dsel;
    base[(size_t)t * UU + cstoS] = nt;
    const float dref = __uint_as_float(
        (unsigned)__builtin_amdgcn_readfirstlane(__float_as_int(d)));
    const bool uni = (__ballot(fabsf(d - dref) <= TAU) == ~0ull);
    trueP = nt;
    specP = specRow;
    if (uni) { ts_rec = t; c_rec = dref; break; }
  }
  if (lane == 0) { g_ts[b * 7 + j - 1] = ts_rec; g_c[b * 7 + j - 1] = c_rec; }
#else
  if (lane == 0) { g_ts[b * 7 + j - 1] = segEnd; g_c[b * 7 + j - 1] = 0.0f; }
#endif
}

// ---------------------------------------------------------------------------
// off(b,row) helper algebra (shared by K3/K4): row<=256 -> 0; segment
// j=(row-1)>>8 in 1..7: rows [jr, ts_j] -> C[j-1], (ts_j, segEnd] -> C[j].
// ---------------------------------------------------------------------------

// K3: backpointers; applies alpha offsets during the LDS load (row-uniform
// adds don't change the per-(t,u) argmax; stored alphas need them to be the
// TRUE values used by score/backtrace semantics).
__global__ __launch_bounds__(256) void k3_bp(const float* __restrict__ lb,
                                             const float* __restrict__ trans,
                                             const int* __restrict__ nwords,
                                             unsigned char* __restrict__ bp) {
  __shared__ float as[129 * 32];
  __shared__ float ts[32 * 32];
  const int b = blockIdx.x >> 4;
  const int c = blockIdx.x & 15;
  const int t0 = 128 * c;
  const int tid = threadIdx.x;
  const float* base = lb + (size_t)b * TT * UU;
  const int nw = nwords[b];

  float C[8];
  int TS[8];
  C[0] = 0.0f; TS[0] = 0;
#pragma unroll
  for (int j = 1; j <= 7; ++j) {
    C[j] = C[j - 1] + g_c[b * 7 + j - 1];
    TS[j] = g_ts[b * 7 + j - 1];
  }

  for (int idx = tid; idx < 129 * 32; idx += 256) {
    const int gidx = (t0 - 1) * 32 + idx;
    float v = 0.0f;
    if (gidx >= 0 && gidx < TT * UU) {
      const int row = (t0 - 1) + (idx >> 5);
      const int jj = (row - 1) >> 8;          // 0 for rows 0..256
      float off = 0.0f;
      if (jj >= 1) off = (row <= TS[jj]) ? C[jj - 1] : C[jj];
      v = base[gidx] + off;
    }
    as[idx] = v;
  }
  for (int idx = tid; idx < 1024; idx += 256) ts[idx] = trans[idx];
  __syncthreads();

  const int u = tid & 31;
  const int tg = tid >> 5;
  unsigned char* bpu = bp + ((size_t)b * 32 + u) * TT;

#pragma unroll 1
  for (int qq = 0; qq < 4; ++qq) {
    const int tl0 = tg * 16 + qq * 4;
    unsigned int pack = 0;
#pragma unroll
    for (int e = 0; e < 4; ++e) {
      const int tl = tl0 + e;
      const int t = t0 + tl;
      int idx;
      if (t >= 1 && t < nw) {
        float m = as[tl * 32 + 0] + ts[0 * 32 + u];
        idx = 0;
#pragma unroll
        for (int v = 1; v < 32; ++v) {
          const float cv = as[tl * 32 + v] + ts[v * 32 + u];
          if (cv > m) { m = cv; idx = v; }
        }
      } else {
        idx = u;
      }
      pack |= ((unsigned int)idx) << (8 * e);
    }
    *(unsigned int*)(bpu + t0 + tl0) = pack;
  }
}

// ---------------------------------------------------------------------------
// K4: backtrace + best_score; applies off(nw-1) to its single alpha row read.
// ---------------------------------------------------------------------------
__global__ __launch_bounds__(64) void k4_backtrace(const float* __restrict__ lb,
                                                   const unsigned char* __restrict__ bp,
                                                   const int* __restrict__ nwords,
                                                   int* __restrict__ pred,
                                                   float* __restrict__ score) {
  const int b = blockIdx.x;
  const int lane = threadIdx.x;
  const int u = lane & 31;
  const int h = lane >> 5;
  const int nw = nwords[b];

  float off = 0.0f;
  {
    const int row = nw - 1;
    const int jj = (row - 1) >> 8;
    if (jj >= 1) {
      float Cacc = 0.0f;
      float Cprev = 0.0f;
#pragma unroll
      for (int j = 1; j <= 7; ++j) {
        Cprev = Cacc;
        Cacc += g_c[b * 7 + j - 1];
        if (j == jj) off = (row <= g_ts[b * 7 + j - 1]) ? Cprev : Cacc;
      }
    }
  }

  const float a = lb[((size_t)b * TT + (nw - 1)) * UU + u] + off;
  float m = a;
#pragma unroll
  for (int s = 32; s; s >>= 1) m = fmaxf(m, __shfl_xor(m, s));
  if (lane == 0) score[b] = m;
  const unsigned long long mask = __ballot(lane < 32 && a == m);
  int tag = __ffsll((unsigned long long)mask) - 1;
  tag = __builtin_amdgcn_readfirstlane(tag);

  int* predb = pred + b * TT;
  for (int p = nw - 1 + lane; p < TT; p += 64) predb[p] = tag;
  if (nw < 2) return;

  const unsigned char* bpb = bp + (size_t)b * 32 * TT;
  const int pcmax = (nw - 2) >> 6;
  const int thi_top = nw - 1;

  int wprev0 = 0;
  {
    const int toff = (pcmax + 1) * 64;
    if (toff < TT) wprev0 = *(const int*)(bpb + (size_t)u * TT + toff);
  }

  for (int pc = pcmax; pc >= 0; --pc) {
    int wreg[8];
#pragma unroll
    for (int j = 0; j < 8; ++j)
      wreg[j] = *(const int*)(bpb + (size_t)u * TT + pc * 64 + 4 * (h * 8 + j));
    int predv = 0;

    if (pc == pcmax) {
      const int thi = thi_top;
      if (pc * 64 + 64 <= thi) {
        const int val = __builtin_amdgcn_readlane(wprev0, tag);
        tag = __builtin_amdgcn_readfirstlane(val & 0xFF);
        if (lane == 63) predv = tag;
      }
#pragma unroll
      for (int lt = 63; lt >= 1; --lt) {
        if (pc * 64 + lt <= thi) {
          const int d = lt >> 2, byte = lt & 3;
          const int hs = d >> 3, j = d & 7;
          const int val = __builtin_amdgcn_readlane(wreg[j], hs * 32 + tag);
          tag = __builtin_amdgcn_readfirstlane((val >> (8 * byte)) & 0xFF);
          if (lane == lt - 1) predv = tag;
        }
      }
      const int lim = thi - pc * 64;
      if (lane < lim) predb[pc * 64 + lane] = predv;
    } else {
      {
        const int val = __builtin_amdgcn_readlane(wprev0, tag);
        tag = __builtin_amdgcn_readfirstlane(val & 0xFF);
        if (lane == 63) predv = tag;
      }
#pragma unroll
      for (int lt = 63; lt >= 1; --lt) {
        const int d = lt >> 2, byte = lt & 3;
        const int hs = d >> 3, j = d & 7;
        const int val = __builtin_amdgcn_readlane(wreg[j], hs * 32 + tag);
        tag = __builtin_amdgcn_readfirstlane((val >> (8 * byte)) & 0xFF);
        if (lane == lt - 1) predv = tag;
      }
      predb[pc * 64 + lane] = predv;
    }
    wprev0 = wreg[0];
  }
}

// ---------------------------------------------------------------------------
extern "C" void kernel_launch(void* const* d_in, const int* in_sizes, int n_in,
                              void* d_out, int out_size, void* d_ws, size_t ws_size,
                              hipStream_t stream) {
  const float* x = (const float*)d_in[0];
  const int* nwords = (const int*)d_in[1];
  const float* kern = (const float*)d_in[2];
  const float* chain = (const float*)d_in[3];
  const float* bias = (const float*)d_in[4];

  float* logits = (float*)d_ws;                                        // 16 MB
  unsigned char* bp = (unsigned char*)d_ws + (size_t)BB * TT * UU * 4; // +4 MB

  int* pred = (int*)d_out;
  float* score = (float*)d_out + (size_t)BB * TT;

  k1_logits<<<dim3(512), dim3(256), 0, stream>>>(x, kern, bias, logits);
  k2a_forward<<<dim3(512), dim3(64), 0, stream>>>(logits, chain);
  k2b_fixup<<<dim3(448), dim3(64), 0, stream>>>(logits, chain);
  k3_bp<<<dim3(BB * 16), dim3(256), 0, stream>>>(logits, chain, nwords, bp);
  k4_backtrace<<<dim3(BB), dim3(64), 0, stream>>>(logits, bp, nwords, pred, score);
}

// Round 16
// 172.765 us; speedup vs baseline: 2.2046x; 1.0346x over previous
//
#include <hip/hip_runtime.h>

#define BB 64
#define TT 2048
#define DD 512
#define UU 32

// Speculation geometry: NSEG segments of SEGLEN rows; junction j (1..NJ) at
// row SEGLEN*j+1. Chained-parallel scans (R14-verified algebra):
//   C[0]=0, C[j]=C[j-1]+c'_j; rows [jr_j, ts_j] hold true-C[j-1], rows
//   (ts_j, E_j] hold spec = true-C[j]. Offsets applied at read time in k3/k4.
#define NSEG 16
#define SEGLEN 128            // TT/NSEG
#define SEGSH 7               // log2(SEGLEN)
#define NJ (NSEG - 1)

__device__ int g_ts[BB * NJ];
__device__ float g_c[BB * NJ];
__device__ float g_bound[BB * NSEG * 64];

// ---------------------------------------------------------------------------
// K1: logits GEMM (R15-verified: 256-row geometry + k-pair x-reads).
// ---------------------------------------------------------------------------
__global__ __launch_bounds__(256) void k1_logits(const float* __restrict__ x,
                                                 const float* __restrict__ w,
                                                 const float* __restrict__ bias,
                                                 float* __restrict__ out) {
  __shared__ float xs[256 * 34];
  __shared__ float wsh[32 * 36];
  const int tid = threadIdx.x;
  const long row0 = (long)blockIdx.x * 256;
  const int tr = tid >> 2;
  const int tc = tid & 3;
  const int ubase = tc * 8;
  const int sr = tid >> 3;
  const int sc = (tid & 7) * 4;

  float acc[4][8];
#pragma unroll
  for (int i = 0; i < 4; ++i)
#pragma unroll
    for (int j = 0; j < 8; ++j) acc[i][j] = 0.0f;

  for (int kc = 0; kc < DD; kc += 32) {
#pragma unroll
    for (int p = 0; p < 8; ++p) {
      const int r = p * 32 + sr;
      const float4 v = *(const float4*)(x + (row0 + r) * DD + kc + sc);
      *(float2*)(&xs[r * 34 + sc]) = make_float2(v.x, v.y);
      *(float2*)(&xs[r * 34 + sc + 2]) = make_float2(v.z, v.w);
    }
    {
      const int k = tid >> 3;
      const int uu4 = (tid & 7) * 4;
      const float4 v = *(const float4*)(w + (size_t)(kc + k) * UU + uu4);
      *(float4*)(&wsh[k * 36 + uu4]) = v;
    }
    __syncthreads();
#pragma unroll
    for (int kp = 0; kp < 16; ++kp) {
      const int k = kp * 2;
      const float4 wa0 = *(const float4*)(&wsh[k * 36 + ubase]);
      const float4 wa1 = *(const float4*)(&wsh[k * 36 + ubase + 4]);
      const float4 wb0 = *(const float4*)(&wsh[(k + 1) * 36 + ubase]);
      const float4 wb1 = *(const float4*)(&wsh[(k + 1) * 36 + ubase + 4]);
      const float wva[8] = {wa0.x, wa0.y, wa0.z, wa0.w, wa1.x, wa1.y, wa1.z, wa1.w};
      const float wvb[8] = {wb0.x, wb0.y, wb0.z, wb0.w, wb1.x, wb1.y, wb1.z, wb1.w};
#pragma unroll
      for (int i = 0; i < 4; ++i) {
        const float2 xv2 = *(const float2*)(&xs[(tr + 64 * i) * 34 + k]);
#pragma unroll
        for (int j = 0; j < 8; ++j) acc[i][j] = fmaf(xv2.x, wva[j], acc[i][j]);
#pragma unroll
        for (int j = 0; j < 8; ++j) acc[i][j] = fmaf(xv2.y, wvb[j], acc[i][j]);
      }
    }
    __syncthreads();
  }
  float bv[8];
#pragma unroll
  for (int j = 0; j < 8; ++j) bv[j] = bias[ubase + j];
#pragma unroll
  for (int i = 0; i < 4; ++i) {
    const long row = row0 + tr + 64 * i;
    float4 o0, o1;
    o0.x = acc[i][0] + bv[0]; o0.y = acc[i][1] + bv[1];
    o0.z = acc[i][2] + bv[2]; o0.w = acc[i][3] + bv[3];
    o1.x = acc[i][4] + bv[4]; o1.y = acc[i][5] + bv[5];
    o1.z = acc[i][6] + bv[6]; o1.w = acc[i][7] + bv[7];
    *(float4*)(out + row * UU + ubase) = o0;
    *(float4*)(out + row * UU + ubase + 4) = o1;
  }
}

// ======================= K2 common machinery (R7-verified) ==================

#define ROTF(S) \
  __int_as_float(__builtin_amdgcn_update_dpp(0, __float_as_int(P), 0x120 + (S), 0xF, 0xF, true))

#define K2_TREE                                                              \
    const float c0 = P + tvS[0];                                             \
    const float c1 = ROTF(1) + tvS[1];                                       \
    const float c2 = ROTF(2) + tvS[2];                                       \
    const float c3 = ROTF(3) + tvS[3];                                       \
    const float c4 = ROTF(4) + tvS[4];                                       \
    const float c5 = ROTF(5) + tvS[5];                                       \
    const float c6 = ROTF(6) + tvS[6];                                       \
    const float c7 = ROTF(7) + tvS[7];                                       \
    const float c8 = ROTF(8) + tvS[8];                                       \
    const float c9 = ROTF(9) + tvS[9];                                       \
    const float c10 = ROTF(10) + tvS[10];                                    \
    const float c11 = ROTF(11) + tvS[11];                                    \
    const float c12 = ROTF(12) + tvS[12];                                    \
    const float c13 = ROTF(13) + tvS[13];                                    \
    const float c14 = ROTF(14) + tvS[14];                                    \
    const float c15 = ROTF(15) + tvS[15];                                    \
    const float d0 = fmaxf(fmaxf(c0, c1), c2);                               \
    const float d1 = fmaxf(fmaxf(c3, c4), c5);                               \
    const float d2 = fmaxf(fmaxf(c6, c7), c8);                               \
    const float d3 = fmaxf(fmaxf(c9, c10), c11);                             \
    const float d4 = fmaxf(fmaxf(c12, c13), c14);                            \
    const float e0 = fmaxf(fmaxf(d0, d1), d2);                               \
    const float e1 = fmaxf(fmaxf(d3, d4), c15);                              \
    const float pm = fmaxf(e0, e1);

#if __has_builtin(__builtin_amdgcn_permlane32_swap) && __has_builtin(__builtin_amdgcn_permlane16_swap)
#define K2_HAVE_PERMLANE 1
typedef unsigned int v2u __attribute__((ext_vector_type(2)));

#define K2_FSTEP(tval, lg) do {                                              \
    K2_TREE                                                                  \
    v2u s32 = __builtin_amdgcn_permlane32_swap(__float_as_uint(pm),          \
                                               __float_as_uint(pm), false, false); \
    const float pd = fmaxf(__uint_as_float(s32.x), __uint_as_float(s32.y)) + (lg); \
    v2u s16 = __builtin_amdgcn_permlane16_swap(__float_as_uint(pd),          \
                                               __float_as_uint(pd), false, false); \
    const float cx = m16sel ? __uint_as_float(s16.x) : __uint_as_float(s16.y); \
    P = bit5v ? cx : pd;                                                     \
    base[(size_t)(tval) * UU + cstoS] = P;                                   \
  } while (0)

// combined pre-logit max (bitwise-identical tree + swap32 fold of K2_FSTEP)
__device__ __forceinline__ float k2_mcomb(float P, const float* tvS) {
  K2_TREE
  v2u s32 = __builtin_amdgcn_permlane32_swap(__float_as_uint(pm),
                                             __float_as_uint(pm), false, false);
  return fmaxf(__uint_as_float(s32.x), __uint_as_float(s32.y));
}

// generic segment runner: steps rows [A_,E_] with live P (clamped prefetch,
// no reads beyond E_ -> no cross-role races in k2a).
#define K2_RUNSEG(A_, E_) do {                                               \
    int tcc = (A_);                                                          \
    _Pragma("unroll")                                                        \
    for (int i = 0; i < 16; ++i) {                                           \
      int r = (A_) + i; if (r > (E_)) r = (E_);                              \
      bufA[i] = base[(size_t)r * UU + tgtS];                                 \
    }                                                                        \
    _Pragma("unroll 1")                                                      \
    for (; tcc + 31 <= (E_); tcc += 32) {                                    \
      _Pragma("unroll")                                                      \
      for (int i = 0; i < 16; ++i) bufB[i] = base[(size_t)(tcc + 16 + i) * UU + tgtS]; \
      _Pragma("unroll")                                                      \
      for (int i = 0; i < 16; ++i) K2_FSTEP(tcc + i, bufA[i]);               \
      _Pragma("unroll")                                                      \
      for (int i = 0; i < 16; ++i) {                                         \
        int r = tcc + 32 + i; if (r > (E_)) r = (E_);                        \
        bufA[i] = base[(size_t)r * UU + tgtS];                               \
      }                                                                      \
      _Pragma("unroll")                                                      \
      for (int i = 0; i < 16; ++i) K2_FSTEP(tcc + 16 + i, bufB[i]);          \
    }                                                                        \
    const int rem = (E_) - tcc + 1;                                          \
    if (rem > 0) {                                                           \
      _Pragma("unroll")                                                      \
      for (int i = 0; i < 16; ++i) {                                         \
        int r = tcc + 16 + i; if (r > (E_)) r = (E_);                        \
        bufB[i] = base[(size_t)r * UU + tgtS];                               \
      }                                                                      \
      _Pragma("unroll")                                                      \
      for (int i = 0; i < 16; ++i) { if (i < rem) K2_FSTEP(tcc + i, bufA[i]); } \
      _Pragma("unroll")                                                      \
      for (int i = 0; i < 16; ++i) { if (16 + i < rem) K2_FSTEP(tcc + 16 + i, bufB[i]); } \
    }                                                                        \
  } while (0)
#endif

// ---------------------------------------------------------------------------
// K2a: S=NSEG speculation. NSEG*64 blocks.
//  role 0: TRUE rows 1..SEGLEN; saves boundary vector to g_bound slot 0.
//  role j: SPECULATIVE from fresh start at logits[SEGLEN*j+1] (junction row
//  untouched), rows SEGLEN*j+2..E_j; saves boundary vector to slot j.
// ---------------------------------------------------------------------------
__global__ __launch_bounds__(64) void k2a_forward(float* __restrict__ lb,
                                                  const float* __restrict__ trans) {
  const int lane = threadIdx.x;
  const int q = lane & 15;
  const int bit4 = (lane >> 4) & 1;
  const int bit5v = (lane >> 5) & 1;
  const int hiS = bit4 ^ bit5v;
  const int tgtS = bit4 * 16 + q;
  const int cstoS = hiS * 16 + q;
  const int role = blockIdx.x >> 6;
  const int b = blockIdx.x & 63;

  const int probe = __builtin_amdgcn_update_dpp(0, q, 0x121, 0xF, 0xF, false);
  const bool dirp = (probe == ((q + 1) & 15));

  float tvS[16];
#pragma unroll
  for (int s = 0; s < 16; ++s) {
    const int rp = dirp ? ((q + s) & 15) : ((q - s) & 15);
    tvS[s] = trans[(hiS * 16 + rp) * UU + tgtS];
  }

  float* base = lb + (size_t)b * TT * UU;
  float bufA[16], bufB[16];

#ifdef K2_HAVE_PERMLANE
  v2u p32 = __builtin_amdgcn_permlane32_swap((unsigned)lane, (unsigned)lane, false, false);
  v2u p16 = __builtin_amdgcn_permlane16_swap((unsigned)lane, (unsigned)lane, false, false);
  const bool c32ok = ((int)p32.x == (lane ^ 32)) || ((int)p32.y == (lane ^ 32));
  const bool c16ok = ((int)p16.x == (lane ^ 16)) || ((int)p16.y == (lane ^ 16));
  const bool m16sel = ((int)p16.x == (lane ^ 16));
  const bool okSwap = (__ballot(c32ok) == ~0ull) && (__ballot(c16ok) == ~0ull);

  if (okSwap) {
    if (role == 0) {
      float P = base[cstoS];
      K2_RUNSEG(1, SEGLEN);
      g_bound[((b << 4) + 0) * 64 + lane] = P;
    } else {
      const int s0 = SEGLEN * role + 1;
      const int E = (role < NJ) ? (SEGLEN * (role + 1)) : (TT - 1);
      float P = base[(size_t)s0 * UU + cstoS];
      K2_RUNSEG(s0 + 1, E);
      g_bound[((b << 4) + role) * 64 + lane] = P;
    }
    return;
  }
#endif

  // ---------------- fallback: R2 bpermute alternating S/D scheme, FULL chain
  if (role != 0) return;
  {
    float tvD[16];
#pragma unroll
    for (int s = 0; s < 16; ++s) {
      const int rp = dirp ? ((q + s) & 15) : ((q - s) & 15);
      tvD[s] = trans[(bit4 * 16 + rp) * UU + cstoS];
    }
    const int idx32 = (lane ^ 32) << 2;
    const int idx48 = (lane ^ 48) << 2;
    float P = base[cstoS];

#define K2_BSTEP(tval, lg, TVHI, XIDX, SCOL) do {                            \
    const float g0 = P + (TVHI)[0];                                          \
    const float g1 = ROTF(1) + (TVHI)[1];                                    \
    const float g2 = ROTF(2) + (TVHI)[2];                                    \
    const float g3 = ROTF(3) + (TVHI)[3];                                    \
    const float g4 = ROTF(4) + (TVHI)[4];                                    \
    const float g5 = ROTF(5) + (TVHI)[5];                                    \
    const float g6 = ROTF(6) + (TVHI)[6];                                    \
    const float g7 = ROTF(7) + (TVHI)[7];                                    \
    const float g8 = ROTF(8) + (TVHI)[8];                                    \
    const float g9 = ROTF(9) + (TVHI)[9];                                    \
    const float g10 = ROTF(10) + (TVHI)[10];                                 \
    const float g11 = ROTF(11) + (TVHI)[11];                                 \
    const float g12 = ROTF(12) + (TVHI)[12];                                 \
    const float g13 = ROTF(13) + (TVHI)[13];                                 \
    const float g14 = ROTF(14) + (TVHI)[14];                                 \
    const float g15 = ROTF(15) + (TVHI)[15];                                 \
    const float h0 = fmaxf(fmaxf(g0, g1), g2);                               \
    const float h1 = fmaxf(fmaxf(g3, g4), g5);                               \
    const float h2 = fmaxf(fmaxf(g6, g7), g8);                               \
    const float h3 = fmaxf(fmaxf(g9, g10), g11);                             \
    const float h4 = fmaxf(fmaxf(g12, g13), g14);                            \
    const float k0 = fmaxf(fmaxf(h0, h1), h2);                               \
    const float k1 = fmaxf(fmaxf(h3, h4), g15);                              \
    const float pm2 = fmaxf(k0, k1);                                         \
    const int po = __builtin_amdgcn_ds_bpermute((XIDX), __float_as_int(pm2));\
    P = fmaxf(pm2, __int_as_float(po)) + (lg);                               \
    base[(size_t)(tval) * UU + (SCOL)] = P;                                  \
  } while (0)

#pragma unroll
    for (int i = 0; i < 16; ++i)
      bufA[i] = base[(size_t)(1 + i) * UU + ((i & 1) ? cstoS : tgtS)];
#pragma unroll 1
    for (int tc = 1; tc <= 1985; tc += 32) {
#pragma unroll
      for (int i = 0; i < 16; ++i)
        bufB[i] = base[(size_t)(tc + 16 + i) * UU + ((i & 1) ? cstoS : tgtS)];
#pragma unroll
      for (int i = 0; i < 16; ++i) {
        if ((i & 1) == 0) K2_BSTEP(tc + i, bufA[i], tvS, idx32, tgtS);
        else              K2_BSTEP(tc + i, bufA[i], tvD, idx48, cstoS);
      }
#pragma unroll
      for (int i = 0; i < 16; ++i)
        bufA[i] = base[(size_t)(tc + 32 + i) * UU + ((i & 1) ? cstoS : tgtS)];
#pragma unroll
      for (int i = 0; i < 16; ++i) {
        if ((i & 1) == 0) K2_BSTEP(tc + 16 + i, bufB[i], tvS, idx32, tgtS);
        else              K2_BSTEP(tc + 16 + i, bufB[i], tvD, idx48, cstoS);
      }
    }
#pragma unroll
    for (int i = 0; i < 16; ++i) {
      int r = 2033 + i; if (r > TT - 1) r = TT - 1;
      bufB[i] = base[(size_t)r * UU + ((i & 1) ? cstoS : tgtS)];
    }
#pragma unroll
    for (int i = 0; i < 16; ++i) {
      if ((i & 1) == 0) K2_BSTEP(2017 + i, bufA[i], tvS, idx32, tgtS);
      else              K2_BSTEP(2017 + i, bufA[i], tvD, idx48, cstoS);
    }
#pragma unroll
    for (int i = 0; i < 15; ++i) {
      if ((i & 1) == 0) K2_BSTEP(2033 + i, bufB[i], tvS, idx32, tgtS);
      else              K2_BSTEP(2033 + i, bufB[i], tvD, idx48, cstoS);
    }
  }
}

// ---------------------------------------------------------------------------
// K2b: PARALLEL junction scans — NJ*64 blocks, all independent.
// (R14-verified scan loop, byte-identical; geometry parameterized.)
// ---------------------------------------------------------------------------
__global__ __launch_bounds__(64) void k2b_fixup(float* __restrict__ lb,
                                                const float* __restrict__ trans) {
  const int lane = threadIdx.x;
  const int b = blockIdx.x & 63;
  const int j = (blockIdx.x >> 6) + 1;            // 1..NJ
  const int q = lane & 15;
  const int bit4 = (lane >> 4) & 1;
  const int bit5v = (lane >> 5) & 1;
  const int hiS = bit4 ^ bit5v;
  const int tgtS = bit4 * 16 + q;
  const int cstoS = hiS * 16 + q;
  const int jr = SEGLEN * j + 1;
  const int segEnd = (j < NJ) ? (SEGLEN * (j + 1)) : (TT - 1);

  const int probe = __builtin_amdgcn_update_dpp(0, q, 0x121, 0xF, 0xF, false);
  const bool dirp = (probe == ((q + 1) & 15));

  float tvS[16];
#pragma unroll
  for (int s = 0; s < 16; ++s) {
    const int rp = dirp ? ((q + s) & 15) : ((q - s) & 15);
    tvS[s] = trans[(hiS * 16 + rp) * UU + tgtS];
  }

#ifdef K2_HAVE_PERMLANE
  v2u p32 = __builtin_amdgcn_permlane32_swap((unsigned)lane, (unsigned)lane, false, false);
  v2u p16 = __builtin_amdgcn_permlane16_swap((unsigned)lane, (unsigned)lane, false, false);
  const bool c32ok = ((int)p32.x == (lane ^ 32)) || ((int)p32.y == (lane ^ 32));
  const bool c16ok = ((int)p16.x == (lane ^ 16)) || ((int)p16.y == (lane ^ 16));
  const bool m16sel = ((int)p16.x == (lane ^ 16));
  const bool okSwap = (__ballot(c32ok) == ~0ull) && (__ballot(c16ok) == ~0ull);
  if (!okSwap) {
    if (lane == 0) { g_ts[b * NJ + j - 1] = segEnd; g_c[b * NJ + j - 1] = 0.0f; }
    return;  // fallback path computed the full true chain already
  }

  float* base = lb + (size_t)b * TT * UU;
  const float TAU = 0.05f;

  float trueP = g_bound[((b << 4) + (j - 1)) * 64 + lane];  // prev boundary
  const float specInit = base[(size_t)jr * UU + cstoS];     // logits (pre-write)
  const float lgj = base[(size_t)jr * UU + tgtS];
  { float P = trueP; K2_FSTEP(jr, lgj); trueP = P; }        // row jr <- true-rel-ref
  float specP = specInit;

  float ring[4];
#pragma unroll
  for (int i = 0; i < 4; ++i) {
    int r = jr + 1 + i; if (r > segEnd) r = segEnd;
    ring[i] = base[(size_t)r * UU + cstoS];
  }
  int ts_rec = segEnd; float c_rec = 0.0f;
#pragma unroll 1
  for (int t = jr + 1; t <= segEnd; ++t) {
    const float specRow = ring[(t - (jr + 1)) & 3];
    const int pf = t + 4;
    if (pf <= segEnd) ring[(t - (jr + 1)) & 3] = base[(size_t)pf * UU + cstoS];
    const float Mt = k2_mcomb(trueP, tvS);
    const float Ms = k2_mcomb(specP, tvS);
    const float d = Mt - Ms;
    v2u s16d = __builtin_amdgcn_permlane16_swap(__float_as_uint(d),
                                                __float_as_uint(d), false, false);
    const float dx = m16sel ? __uint_as_float(s16d.x) : __uint_as_float(s16d.y);
    const float dsel = bit5v ? dx : d;
    const float nt = specRow + dsel;
    base[(size_t)t * UU + cstoS] = nt;
    const float dref = __uint_as_float(
        (unsigned)__builtin_amdgcn_readfirstlane(__float_as_int(d)));
    const bool uni = (__ballot(fabsf(d - dref) <= TAU) == ~0ull);
    trueP = nt;
    specP = specRow;
    if (uni) { ts_rec = t; c_rec = dref; break; }
  }
  if (lane == 0) { g_ts[b * NJ + j - 1] = ts_rec; g_c[b * NJ + j - 1] = c_rec; }
#else
  if (lane == 0) { g_ts[b * NJ + j - 1] = segEnd; g_c[b * NJ + j - 1] = 0.0f; }
#endif
}

// ---------------------------------------------------------------------------
// K3: backpointers; applies alpha offsets during the LDS load (row-uniform
// adds don't change the per-(t,u) argmax). off(row): jj=(row-1)>>SEGSH;
// jj==0 -> 0; else rows [jr,ts_jj] -> C[jj-1], (ts_jj, E_jj] -> C[jj].
// ---------------------------------------------------------------------------
__global__ __launch_bounds__(256) void k3_bp(const float* __restrict__ lb,
                                             const float* __restrict__ trans,
                                             const int* __restrict__ nwords,
                                             unsigned char* __restrict__ bp) {
  __shared__ float as[129 * 32];
  __shared__ float ts[32 * 32];
  const int b = blockIdx.x >> 4;
  const int c = blockIdx.x & 15;
  const int t0 = 128 * c;
  const int tid = threadIdx.x;
  const float* base = lb + (size_t)b * TT * UU;
  const int nw = nwords[b];

  float C[NSEG];
  int TS[NSEG];
  C[0] = 0.0f; TS[0] = 0;
#pragma unroll
  for (int j = 1; j <= NJ; ++j) {
    C[j] = C[j - 1] + g_c[b * NJ + j - 1];
    TS[j] = g_ts[b * NJ + j - 1];
  }

  for (int idx = tid; idx < 129 * 32; idx += 256) {
    const int gidx = (t0 - 1) * 32 + idx;
    float v = 0.0f;
    if (gidx >= 0 && gidx < TT * UU) {
      const int row = (t0 - 1) + (idx >> 5);
      const int jj = (row - 1) >> SEGSH;      // 0 for rows 0..SEGLEN
      float off = 0.0f;
      if (jj >= 1) off = (row <= TS[jj]) ? C[jj - 1] : C[jj];
      v = base[gidx] + off;
    }
    as[idx] = v;
  }
  for (int idx = tid; idx < 1024; idx += 256) ts[idx] = trans[idx];
  __syncthreads();

  const int u = tid & 31;
  const int tg = tid >> 5;
  unsigned char* bpu = bp + ((size_t)b * 32 + u) * TT;

#pragma unroll 1
  for (int qq = 0; qq < 4; ++qq) {
    const int tl0 = tg * 16 + qq * 4;
    unsigned int pack = 0;
#pragma unroll
    for (int e = 0; e < 4; ++e) {
      const int tl = tl0 + e;
      const int t = t0 + tl;
      int idx;
      if (t >= 1 && t < nw) {
        float m = as[tl * 32 + 0] + ts[0 * 32 + u];
        idx = 0;
#pragma unroll
        for (int v = 1; v < 32; ++v) {
          const float cv = as[tl * 32 + v] + ts[v * 32 + u];
          if (cv > m) { m = cv; idx = v; }
        }
      } else {
        idx = u;
      }
      pack |= ((unsigned int)idx) << (8 * e);
    }
    *(unsigned int*)(bpu + t0 + tl0) = pack;
  }
}

// ---------------------------------------------------------------------------
// K4: backtrace + best_score; applies off(nw-1) to its single alpha row read.
// ---------------------------------------------------------------------------
__global__ __launch_bounds__(64) void k4_backtrace(const float* __restrict__ lb,
                                                   const unsigned char* __restrict__ bp,
                                                   const int* __restrict__ nwords,
                                                   int* __restrict__ pred,
                                                   float* __restrict__ score) {
  const int b = blockIdx.x;
  const int lane = threadIdx.x;
  const int u = lane & 31;
  const int h = lane >> 5;
  const int nw = nwords[b];

  float off = 0.0f;
  {
    const int row = nw - 1;
    const int jj = (row - 1) >> SEGSH;
    if (jj >= 1) {
      float Cacc = 0.0f;
      float Cprev = 0.0f;
#pragma unroll
      for (int j = 1; j <= NJ; ++j) {
        Cprev = Cacc;
        Cacc += g_c[b * NJ + j - 1];
        if (j == jj) off = (row <= g_ts[b * NJ + j - 1]) ? Cprev : Cacc;
      }
    }
  }

  const float a = lb[((size_t)b * TT + (nw - 1)) * UU + u] + off;
  float m = a;
#pragma unroll
  for (int s = 32; s; s >>= 1) m = fmaxf(m, __shfl_xor(m, s));
  if (lane == 0) score[b] = m;
  const unsigned long long mask = __ballot(lane < 32 && a == m);
  int tag = __ffsll((unsigned long long)mask) - 1;
  tag = __builtin_amdgcn_readfirstlane(tag);

  int* predb = pred + b * TT;
  for (int p = nw - 1 + lane; p < TT; p += 64) predb[p] = tag;
  if (nw < 2) return;

  const unsigned char* bpb = bp + (size_t)b * 32 * TT;
  const int pcmax = (nw - 2) >> 6;
  const int thi_top = nw - 1;

  int wprev0 = 0;
  {
    const int toff = (pcmax + 1) * 64;
    if (toff < TT) wprev0 = *(const int*)(bpb + (size_t)u * TT + toff);
  }

  for (int pc = pcmax; pc >= 0; --pc) {
    int wreg[8];
#pragma unroll
    for (int j = 0; j < 8; ++j)
      wreg[j] = *(const int*)(bpb + (size_t)u * TT + pc * 64 + 4 * (h * 8 + j));
    int predv = 0;

    if (pc == pcmax) {
      const int thi = thi_top;
      if (pc * 64 + 64 <= thi) {
        const int val = __builtin_amdgcn_readlane(wprev0, tag);
        tag = __builtin_amdgcn_readfirstlane(val & 0xFF);
        if (lane == 63) predv = tag;
      }
#pragma unroll
      for (int lt = 63; lt >= 1; --lt) {
        if (pc * 64 + lt <= thi) {
          const int d = lt >> 2, byte = lt & 3;
          const int hs = d >> 3, j = d & 7;
          const int val = __builtin_amdgcn_readlane(wreg[j], hs * 32 + tag);
          tag = __builtin_amdgcn_readfirstlane((val >> (8 * byte)) & 0xFF);
          if (lane == lt - 1) predv = tag;
        }
      }
      const int lim = thi - pc * 64;
      if (lane < lim) predb[pc * 64 + lane] = predv;
    } else {
      {
        const int val = __builtin_amdgcn_readlane(wprev0, tag);
        tag = __builtin_amdgcn_readfirstlane(val & 0xFF);
        if (lane == 63) predv = tag;
      }
#pragma unroll
      for (int lt = 63; lt >= 1; --lt) {
        const int d = lt >> 2, byte = lt & 3;
        const int hs = d >> 3, j = d & 7;
        const int val = __builtin_amdgcn_readlane(wreg[j], hs * 32 + tag);
        tag = __builtin_amdgcn_readfirstlane((val >> (8 * byte)) & 0xFF);
        if (lane == lt - 1) predv = tag;
      }
      predb[pc * 64 + lane] = predv;
    }
    wprev0 = wreg[0];
  }
}

// ---------------------------------------------------------------------------
extern "C" void kernel_launch(void* const* d_in, const int* in_sizes, int n_in,
                              void* d_out, int out_size, void* d_ws, size_t ws_size,
                              hipStream_t stream) {
  const float* x = (const float*)d_in[0];
  const int* nwords = (const int*)d_in[1];
  const float* kern = (const float*)d_in[2];
  const float* chain = (const float*)d_in[3];
  const float* bias = (const float*)d_in[4];

  float* logits = (float*)d_ws;                                        // 16 MB
  unsigned char* bp = (unsigned char*)d_ws + (size_t)BB * TT * UU * 4; // +4 MB

  int* pred = (int*)d_out;
  float* score = (float*)d_out + (size_t)BB * TT;

  k1_logits<<<dim3(512), dim3(256), 0, stream>>>(x, kern, bias, logits);
  k2a_forward<<<dim3(NSEG * 64), dim3(64), 0, stream>>>(logits, chain);
  k2b_fixup<<<dim3(NJ * 64), dim3(64), 0, stream>>>(logits, chain);
  k3_bp<<<dim3(BB * 16), dim3(256), 0, stream>>>(logits, chain, nwords, bp);
  k4_backtrace<<<dim3(BB), dim3(64), 0, stream>>>(logits, bp, nwords, pred, score);
}